// Round 1
// baseline (4424.004 us; speedup 1.0000x reference)
//
#include <hip/hip_runtime.h>
#include <hip/hip_bf16.h>
#include <type_traits>

using bf16 = __hip_bfloat16;

constexpr int NPIX = 16384;   // pixels per batch (128*128)
constexpr int CDIM = 128;

// ---- workspace offsets (bytes), all 256-aligned ----
constexpr size_t OFF_MU    = 0;         // 131072 f32 (LN1 mean, all batches)
constexpr size_t OFF_RSTD  = 524288;    // 131072 f32
constexpr size_t OFF_MU2   = 1048576;   // 16384 f32 (per-batch, reused)
constexpr size_t OFF_RSTD2 = 1114112;   // 16384 f32
constexpr size_t OFF_SSQ   = 1179648;   // 8*256 f32 sumsq for q,k rows
constexpr size_t OFF_S     = 1187840;   // 8*8*16*16 f32 raw scores
constexpr size_t OFF_WQKV  = 1253376;   // 384*128 f32 packed
constexpr size_t OFF_DWP   = 1449984;   // 384*9 f32 packed dw weights
constexpr size_t OFF_WEFF  = 1463808;   // 128*128 f32 (per-batch, reused)
constexpr size_t OFF_X2B   = 1529344;   // 128*16384 bf16 (per-batch)
constexpr size_t OFF_QKV   = 5723648;   // 384*16384 bf16 (per-batch)
constexpr size_t OFF_QKVDW = 18306560;  // 384*16384 bf16 (per-batch)
constexpr size_t OFF_G     = 5723648;   // 1024*16384 bf16 (overlaps QKV/QKVDW, dead by then)
constexpr size_t OFF_Y     = 39278080;  // 512*16384 bf16
// total ~56 MB

// -------------------- pack weights --------------------
__global__ void pack_w(const float* __restrict__ wq, const float* __restrict__ wk,
                       const float* __restrict__ wv, const float* __restrict__ dwq,
                       const float* __restrict__ dwk, const float* __restrict__ dwv,
                       float* __restrict__ Wqkv, float* __restrict__ dwp) {
    int i = blockIdx.x * 256 + threadIdx.x;
    if (i < 384 * 128) {
        int r = i >> 7, c = i & 127;
        float v = (r < 128) ? wq[r * 128 + c] : (r < 256) ? wk[(r - 128) * 128 + c]
                                                          : wv[(r - 256) * 128 + c];
        Wqkv[i] = v;
    }
    if (i < 384 * 9) {
        int r = i / 9, j = i % 9;
        dwp[i] = (r < 128) ? dwq[r * 9 + j] : (r < 256) ? dwk[(r - 128) * 9 + j]
                                                        : dwv[(r - 256) * 9 + j];
    }
}

// -------------------- LayerNorm stats (over 128 channels per pixel) --------------------
__device__ inline float ldf(const float* p) { return *p; }
__device__ inline float ldf(const bf16* p) { return __bfloat162float(*p); }

template <typename XT>
__global__ __launch_bounds__(256) void ln_stats(const XT* __restrict__ X,
                                                float* __restrict__ mu,
                                                float* __restrict__ rstd) {
    int n = blockIdx.x * 256 + threadIdx.x;  // 0..16383
    float s = 0.f, s2 = 0.f;
    for (int c = 0; c < CDIM; ++c) {
        float v = ldf(&X[(size_t)c * NPIX + n]);
        s += v; s2 += v * v;
    }
    float m = s * (1.f / CDIM);
    float var = s2 * (1.f / CDIM) - m * m;
    mu[n] = m;
    rstd[n] = rsqrtf(var + 1e-5f);
}

// -------------------- generic pixel GEMM: out[r,n] = sum_k W[r,k]*X[k,n] (+res) ----------
// X may be LN-normalized on load: (x - mu[n]) * rstd[n] * lnw[k] + lnb[k]
template <typename XT, typename OT, typename RT, bool LN, bool RES>
__global__ __launch_bounds__(256) void gemm_px(
    const float* __restrict__ W, const XT* __restrict__ X,
    const float* __restrict__ mu, const float* __restrict__ rstd,
    const float* __restrict__ lnw, const float* __restrict__ lnb,
    const RT* __restrict__ res, OT* __restrict__ out, int K) {
    __shared__ float Wl[64][33];
    __shared__ float Xl[32][65];
    const int t = threadIdx.x;
    const int bm = blockIdx.x, bp = blockIdx.y;
    const int n0 = bp * 64;
    const int tx = t & 15, ty = t >> 4;
    const int wrow = t >> 2, wk0 = (t & 3) * 8;
    const int xr = t >> 3, xp0 = (t & 7) * 8;
    float acc[4][4] = {};

    for (int kc = 0; kc < K; kc += 32) {
        // stage W tile 64x32
        const float* wp = W + (size_t)(bm * 64 + wrow) * K + kc + wk0;
        float4 w0 = *(const float4*)wp;
        float4 w1 = *(const float4*)(wp + 4);
        Wl[wrow][wk0 + 0] = w0.x; Wl[wrow][wk0 + 1] = w0.y;
        Wl[wrow][wk0 + 2] = w0.z; Wl[wrow][wk0 + 3] = w0.w;
        Wl[wrow][wk0 + 4] = w1.x; Wl[wrow][wk0 + 5] = w1.y;
        Wl[wrow][wk0 + 6] = w1.z; Wl[wrow][wk0 + 7] = w1.w;
        // stage X tile 32x64
        const int krow = kc + xr;
        float xv[8];
        const XT* xp = X + (size_t)krow * NPIX + n0 + xp0;
        if constexpr (std::is_same_v<XT, float>) {
            float4 a = *(const float4*)xp;
            float4 b = *(const float4*)(xp + 4);
            xv[0] = a.x; xv[1] = a.y; xv[2] = a.z; xv[3] = a.w;
            xv[4] = b.x; xv[5] = b.y; xv[6] = b.z; xv[7] = b.w;
        } else {
            union { uint4 u; bf16 h[8]; } U;
            U.u = *(const uint4*)xp;
            #pragma unroll
            for (int j = 0; j < 8; ++j) xv[j] = __bfloat162float(U.h[j]);
        }
        if constexpr (LN) {
            float lw = lnw[krow], lb = lnb[krow];
            #pragma unroll
            for (int j = 0; j < 8; ++j) {
                int n = n0 + xp0 + j;
                xv[j] = (xv[j] - mu[n]) * rstd[n] * lw + lb;
            }
        }
        #pragma unroll
        for (int j = 0; j < 8; ++j) Xl[xr][xp0 + j] = xv[j];
        __syncthreads();
        #pragma unroll
        for (int kk = 0; kk < 32; ++kk) {
            float a[4], bb[4];
            #pragma unroll
            for (int i = 0; i < 4; ++i) a[i] = Wl[ty * 4 + i][kk];
            #pragma unroll
            for (int j = 0; j < 4; ++j) bb[j] = Xl[kk][tx * 4 + j];
            #pragma unroll
            for (int i = 0; i < 4; ++i)
                #pragma unroll
                for (int j = 0; j < 4; ++j)
                    acc[i][j] = fmaf(a[i], bb[j], acc[i][j]);
        }
        __syncthreads();
    }
    // epilogue
    #pragma unroll
    for (int i = 0; i < 4; ++i) {
        int r = bm * 64 + ty * 4 + i;
        int nb = n0 + tx * 4;
        float v[4];
        #pragma unroll
        for (int j = 0; j < 4; ++j) v[j] = acc[i][j];
        if constexpr (RES) {
            if constexpr (std::is_same_v<RT, float>) {
                float4 rv = *(const float4*)(res + (size_t)r * NPIX + nb);
                v[0] += rv.x; v[1] += rv.y; v[2] += rv.z; v[3] += rv.w;
            } else {
                union { ushort4 u; bf16 h[4]; } R;
                R.u = *(const ushort4*)(res + (size_t)r * NPIX + nb);
                #pragma unroll
                for (int j = 0; j < 4; ++j) v[j] += __bfloat162float(R.h[j]);
            }
        }
        if constexpr (std::is_same_v<OT, float>) {
            *(float4*)(out + (size_t)r * NPIX + nb) = make_float4(v[0], v[1], v[2], v[3]);
        } else {
            union { ushort4 u; bf16 h[4]; } O;
            #pragma unroll
            for (int j = 0; j < 4; ++j) O.h[j] = __float2bfloat16(v[j]);
            *(ushort4*)(out + (size_t)r * NPIX + nb) = O.u;
        }
    }
}

// -------------------- depthwise 3x3 (qkv) + sumsq for q,k rows --------------------
__global__ __launch_bounds__(256) void dwconv_qkv(const bf16* __restrict__ in,
                                                  bf16* __restrict__ out,
                                                  const float* __restrict__ w9,
                                                  float* __restrict__ ssq, int nSsqRows) {
    int bi = blockIdx.x;
    int c = bi >> 6, tile = bi & 63;
    int t = threadIdx.x;
    int y = tile * 2 + (t >> 7), xx = t & 127;
    const bf16* ip = in + (size_t)c * NPIX;
    float w[9];
    #pragma unroll
    for (int j = 0; j < 9; ++j) w[j] = w9[c * 9 + j];
    float acc = 0.f;
    #pragma unroll
    for (int ky = 0; ky < 3; ++ky) {
        int yy = y + ky - 1;
        if (yy < 0 || yy > 127) continue;
        #pragma unroll
        for (int kx = 0; kx < 3; ++kx) {
            int xc = xx + kx - 1;
            if (xc < 0 || xc > 127) continue;
            acc += w[ky * 3 + kx] * __bfloat162float(ip[yy * 128 + xc]);
        }
    }
    out[(size_t)c * NPIX + y * 128 + xx] = __float2bfloat16(acc);
    if (c < nSsqRows) {
        float s2 = acc * acc;
        #pragma unroll
        for (int off = 32; off; off >>= 1) s2 += __shfl_down(s2, off);
        if ((t & 63) == 0) atomicAdd(&ssq[c], s2);
    }
}

// -------------------- raw attention scores: S[d,e] += sum_n q[d,n]*k[e,n] ------------
__global__ __launch_bounds__(256) void attn_scores(const bf16* __restrict__ qkvdw,
                                                   float* __restrict__ S) {
    int h = blockIdx.x, chunk = blockIdx.y;
    int n0 = chunk * 512;
    __shared__ float ql[16][260], kl[16][260];
    int t = threadIdx.x;
    int d = t >> 4, e = t & 15;
    float acc = 0.f;
    for (int sc = 0; sc < 2; ++sc) {
        int nb = n0 + sc * 256;
        int row = t >> 4, c0 = (t & 15) * 16;
        const bf16* qp = qkvdw + (size_t)(h * 16 + row) * NPIX + nb + c0;
        const bf16* kp = qkvdw + (size_t)(128 + h * 16 + row) * NPIX + nb + c0;
        union { uint4 u; bf16 hh[8]; } Q0, Q1, K0, K1;
        Q0.u = *(const uint4*)qp; Q1.u = *(const uint4*)(qp + 8);
        K0.u = *(const uint4*)kp; K1.u = *(const uint4*)(kp + 8);
        #pragma unroll
        for (int j = 0; j < 8; ++j) {
            ql[row][c0 + j] = __bfloat162float(Q0.hh[j]);
            ql[row][c0 + 8 + j] = __bfloat162float(Q1.hh[j]);
            kl[row][c0 + j] = __bfloat162float(K0.hh[j]);
            kl[row][c0 + 8 + j] = __bfloat162float(K1.hh[j]);
        }
        __syncthreads();
        for (int i = 0; i < 256; ++i) acc = fmaf(ql[d][i], kl[e][i], acc);
        __syncthreads();
    }
    atomicAdd(&S[(h * 16 + d) * 16 + e], acc);
}

// -------------------- softmax + W_eff = wo . blockdiag(attn) --------------------
__global__ __launch_bounds__(256) void softmax_weff(const float* __restrict__ S,
                                                    const float* __restrict__ ssq,
                                                    const float* __restrict__ temp,
                                                    const float* __restrict__ wo,
                                                    float* __restrict__ Weff) {
    __shared__ float at[2048];
    __shared__ float rn[256];
    int t = threadIdx.x;
    rn[t] = 1.f / fmaxf(sqrtf(ssq[t]), 1e-12f);
    __syncthreads();
    for (int i = t; i < 2048; i += 256) {
        int hd = i >> 4, e = i & 15, h = hd >> 4;
        at[i] = S[i] * rn[hd] * rn[128 + h * 16 + e] * temp[h];
    }
    __syncthreads();
    if (t < 128) {
        float mx = -1e30f;
        for (int e = 0; e < 16; ++e) mx = fmaxf(mx, at[t * 16 + e]);
        float s = 0.f;
        for (int e = 0; e < 16; ++e) { float v = expf(at[t * 16 + e] - mx); at[t * 16 + e] = v; s += v; }
        float inv = 1.f / s;
        for (int e = 0; e < 16; ++e) at[t * 16 + e] *= inv;
    }
    __syncthreads();
    int o = t >> 1, half = t & 1;
    for (int j = 0; j < 64; ++j) {
        int col = half * 64 + j;
        int h16 = col & ~15, e = col & 15;
        float s = 0.f;
        #pragma unroll
        for (int dd = 0; dd < 16; ++dd)
            s = fmaf(wo[o * 128 + h16 + dd], at[(h16 + dd) * 16 + e], s);
        Weff[o * 128 + col] = s;
    }
}

// -------------------- FFN depthwise 3x3 + GEGLU --------------------
__global__ __launch_bounds__(256) void geglu_dw(const bf16* __restrict__ g,
                                                bf16* __restrict__ y,
                                                const float* __restrict__ dww) {
    int bi = blockIdx.x;
    int c = bi >> 6, tile = bi & 63;
    int t = threadIdx.x;
    int yy0 = tile * 2 + (t >> 7), xx = t & 127;
    const bf16* g1 = g + (size_t)c * NPIX;
    const bf16* g2 = g + (size_t)(c + 512) * NPIX;
    float w1[9], w2[9];
    #pragma unroll
    for (int j = 0; j < 9; ++j) { w1[j] = dww[c * 9 + j]; w2[j] = dww[(c + 512) * 9 + j]; }
    float a1 = 0.f, a2 = 0.f;
    #pragma unroll
    for (int ky = 0; ky < 3; ++ky) {
        int yy = yy0 + ky - 1;
        if (yy < 0 || yy > 127) continue;
        #pragma unroll
        for (int kx = 0; kx < 3; ++kx) {
            int xc = xx + kx - 1;
            if (xc < 0 || xc > 127) continue;
            float i1 = __bfloat162float(g1[yy * 128 + xc]);
            float i2 = __bfloat162float(g2[yy * 128 + xc]);
            a1 = fmaf(w1[ky * 3 + kx], i1, a1);
            a2 = fmaf(w2[ky * 3 + kx], i2, a2);
        }
    }
    float gelu = 0.5f * a1 * (1.f + erff(a1 * 0.70710678118f));
    y[(size_t)c * NPIX + yy0 * 128 + xx] = __float2bfloat16(gelu * a2);
}

// ==================== host ====================
extern "C" void kernel_launch(void* const* d_in, const int* in_sizes, int n_in,
                              void* d_out, int out_size, void* d_ws, size_t ws_size,
                              hipStream_t stream) {
    const float* x    = (const float*)d_in[0];
    const float* ln1w = (const float*)d_in[1];
    const float* ln1b = (const float*)d_in[2];
    const float* wq   = (const float*)d_in[3];
    const float* wk   = (const float*)d_in[4];
    const float* wv   = (const float*)d_in[5];
    const float* dwq  = (const float*)d_in[6];
    const float* dwk  = (const float*)d_in[7];
    const float* dwv  = (const float*)d_in[8];
    const float* temp = (const float*)d_in[9];
    const float* wo   = (const float*)d_in[10];
    const float* ln2w = (const float*)d_in[11];
    const float* ln2b = (const float*)d_in[12];
    const float* w_in = (const float*)d_in[13];
    const float* dwf  = (const float*)d_in[14];
    const float* wout = (const float*)d_in[15];
    float* out = (float*)d_out;
    char* ws = (char*)d_ws;

    float* mu    = (float*)(ws + OFF_MU);
    float* rstd  = (float*)(ws + OFF_RSTD);
    float* mu2   = (float*)(ws + OFF_MU2);
    float* rstd2 = (float*)(ws + OFF_RSTD2);
    float* ssq   = (float*)(ws + OFF_SSQ);
    float* S     = (float*)(ws + OFF_S);
    float* Wqkv  = (float*)(ws + OFF_WQKV);
    float* dwp   = (float*)(ws + OFF_DWP);
    float* Weff  = (float*)(ws + OFF_WEFF);
    bf16*  x2b   = (bf16*)(ws + OFF_X2B);
    bf16*  qkv   = (bf16*)(ws + OFF_QKV);
    bf16*  qkvdw = (bf16*)(ws + OFF_QKVDW);
    bf16*  g     = (bf16*)(ws + OFF_G);
    bf16*  y     = (bf16*)(ws + OFF_Y);

    // zero sumsq + score accumulators (ws is poisoned before every call)
    hipMemsetAsync(ws + OFF_SSQ, 0, 73728, stream);
    pack_w<<<192, 256, 0, stream>>>(wq, wk, wv, dwq, dwk, dwv, Wqkv, dwp);

    for (int b = 0; b < 8; ++b) {
        const float* xb = x + (size_t)b * CDIM * NPIX;
        float* mu_b = mu + b * NPIX;
        float* rstd_b = rstd + b * NPIX;
        float* ssq_b = ssq + b * 256;
        float* S_b = S + b * 2048;
        float* out_b = out + (size_t)b * CDIM * NPIX;

        // LN1 stats
        ln_stats<float><<<64, 256, 0, stream>>>(xb, mu_b, rstd_b);
        // qkv = Wqkv @ LN1(x)
        gemm_px<float, bf16, float, true, false><<<dim3(6, 256), 256, 0, stream>>>(
            Wqkv, xb, mu_b, rstd_b, ln1w, ln1b, nullptr, qkv, 128);
        // depthwise 3x3 + sum-of-squares for q,k rows
        dwconv_qkv<<<384 * 64, 256, 0, stream>>>(qkv, qkvdw, dwp, ssq_b, 256);
        // raw scores
        attn_scores<<<dim3(8, 32), 256, 0, stream>>>(qkvdw, S_b);
        // softmax + fold wo -> W_eff
        softmax_weff<<<1, 256, 0, stream>>>(S_b, ssq_b, temp, wo, Weff);
        // x2 = x + W_eff @ v
        gemm_px<bf16, bf16, float, false, true><<<dim3(2, 256), 256, 0, stream>>>(
            Weff, qkvdw + (size_t)256 * NPIX, nullptr, nullptr, nullptr, nullptr,
            xb, x2b, 128);
        // LN2 stats
        ln_stats<bf16><<<64, 256, 0, stream>>>(x2b, mu2, rstd2);
        // g = w_in @ LN2(x2)
        gemm_px<bf16, bf16, float, true, false><<<dim3(16, 256), 256, 0, stream>>>(
            w_in, x2b, mu2, rstd2, ln2w, ln2b, nullptr, g, 128);
        // depthwise + GEGLU
        geglu_dw<<<512 * 64, 256, 0, stream>>>(g, y, dwf);
        // out = x2 + w_out @ y
        gemm_px<bf16, float, bf16, false, true><<<dim3(2, 256), 256, 0, stream>>>(
            wout, y, nullptr, nullptr, nullptr, nullptr, x2b, out_b, 512);
    }
    (void)in_sizes; (void)n_in; (void)out_size; (void)ws_size;
}

// Round 5
// 1503.403 us; speedup vs baseline: 2.9427x; 2.9427x over previous
//
#include <hip/hip_runtime.h>
#include <hip/hip_bf16.h>
#include <type_traits>

using bf16 = __hip_bfloat16;
using f32x4  = __attribute__((ext_vector_type(4))) float;
using bf16x8 = __attribute__((ext_vector_type(8))) short;

constexpr int NPIX = 16384;   // pixels per batch (128*128)
constexpr int CDIM = 128;

// ---- workspace offsets (bytes), all 256-aligned ----
constexpr size_t OFF_MU    = 0;         // 8*16384 f32
constexpr size_t OFF_RSTD  = 524288;    // 8*16384 f32
constexpr size_t OFF_MU2   = 1048576;   // 16384 f32
constexpr size_t OFF_RSTD2 = 1114112;   // 16384 f32
constexpr size_t OFF_SSQ   = 1179648;   // 8*256 f32
constexpr size_t OFF_S     = 1187840;   // 8*2048 f32
constexpr size_t OFF_DWP   = 1253376;   // 384*9 f32
constexpr size_t OFF_WQKVB = 1267200;   // 384*128 bf16
constexpr size_t OFF_WINB  = 1365504;   // 1024*128 bf16
constexpr size_t OFF_WOUTB = 1627648;   // 128*512 bf16
constexpr size_t OFF_WEFFB = 1758720;   // 128*128 bf16
constexpr size_t OFF_X2B   = 1792000;   // 128*16384 bf16
constexpr size_t OFF_QKV   = 5986304;   // 384*16384 bf16
constexpr size_t OFF_QKVDW = 18569216;  // 384*16384 bf16
constexpr size_t OFF_G     = 5986304;   // 1024*16384 bf16 (overlaps QKV+QKVDW, dead by then)
constexpr size_t OFF_Y     = 39540736;  // 512*16384 bf16
// total ~56.3 MB

__device__ inline float ldf(const float* p) { return *p; }
__device__ inline float ldf(const bf16* p) { return __bfloat162float(*p); }

// -------------------- pack weights to bf16 --------------------
__global__ void pack_w(const float* __restrict__ wq, const float* __restrict__ wk,
                       const float* __restrict__ wv, const float* __restrict__ dwq,
                       const float* __restrict__ dwk, const float* __restrict__ dwv,
                       const float* __restrict__ w_in, const float* __restrict__ wout,
                       bf16* __restrict__ Wqkvb, float* __restrict__ dwp,
                       bf16* __restrict__ winb, bf16* __restrict__ woutb) {
    int i = blockIdx.x * 256 + threadIdx.x;   // grid 512 -> 131072
    if (i < 384 * 128) {
        int r = i >> 7, c = i & 127;
        float v = (r < 128) ? wq[r * 128 + c] : (r < 256) ? wk[(r - 128) * 128 + c]
                                                          : wv[(r - 256) * 128 + c];
        Wqkvb[i] = __float2bfloat16(v);
    }
    if (i < 384 * 9) {
        int r = i / 9, j = i % 9;
        dwp[i] = (r < 128) ? dwq[r * 9 + j] : (r < 256) ? dwk[(r - 128) * 9 + j]
                                                        : dwv[(r - 256) * 9 + j];
    }
    if (i < 1024 * 128) winb[i] = __float2bfloat16(w_in[i]);
    if (i < 128 * 512)  woutb[i] = __float2bfloat16(wout[i]);
}

// -------------------- LayerNorm stats --------------------
template <typename XT>
__global__ __launch_bounds__(256) void ln_stats(const XT* __restrict__ X,
                                                float* __restrict__ mu,
                                                float* __restrict__ rstd) {
    int n = blockIdx.x * 256 + threadIdx.x;
    float s = 0.f, s2 = 0.f;
    for (int c = 0; c < CDIM; ++c) {
        float v = ldf(&X[(size_t)c * NPIX + n]);
        s += v; s2 += v * v;
    }
    float m = s * (1.f / CDIM);
    float var = s2 * (1.f / CDIM) - m * m;
    mu[n] = m;
    rstd[n] = rsqrtf(var + 1e-5f);
}

// ---------------- MFMA GEMM: out[m,n] = sum_k W[m,k]*X[k,n] (+res, +LN-on-X) ----------
// tile 64M x 128N, K-step 32; 4 waves as 2(M)x2(N); wave tile 32x64 = 2x4 16x16 frags.
// A/B frag k-map: k = (lane>>4)*8 + j  (same for both -> any HW bijection cancels).
// C/D map (HW-verified m89): col = lane&15, row = (lane>>4)*4 + reg.
template <typename XT, typename OT, typename RT, bool LN, bool RES>
__global__ __launch_bounds__(256) void gemm_mfma(
    const bf16* __restrict__ Wb, const XT* __restrict__ X,
    const float* __restrict__ mu, const float* __restrict__ rstd,
    const float* __restrict__ lnw, const float* __restrict__ lnb,
    const RT* __restrict__ res, OT* __restrict__ out, int K) {
    __shared__ bf16 Wl[64][40];    // [m][k], row stride 80B (16B-aligned)
    __shared__ bf16 Xt[128][40];   // [n][k] transposed
    const int t = threadIdx.x;
    const int lane = t & 63, wave = t >> 6;
    const int wm = wave >> 1, wn = wave & 1;
    const int g = lane >> 4, lr = lane & 15;
    const int m0 = blockIdx.x * 64, n0 = blockIdx.y * 128;

    const int sw_row = t >> 2, sw_k8 = (t & 3) * 8;  // W staging: 8 bf16 per thread
    const int sx_n = t & 127, sx_kh = t >> 7;        // X staging: 16 k's for one n

    float x_mu = 0.f, x_rs = 0.f;
    if constexpr (LN) { x_mu = mu[n0 + sx_n]; x_rs = rstd[n0 + sx_n]; }

    f32x4 acc[2][4];
    #pragma unroll
    for (int i = 0; i < 2; ++i)
        #pragma unroll
        for (int j = 0; j < 4; ++j)
            acc[i][j] = (f32x4){0.f, 0.f, 0.f, 0.f};

    for (int kc = 0; kc < K; kc += 32) {
        // stage W tile 64x32 (bf16, b128 write)
        uint4 wv = *(const uint4*)(Wb + (size_t)(m0 + sw_row) * K + kc + sw_k8);
        *(uint4*)&Wl[sw_row][sw_k8] = wv;
        // stage X tile transposed: thread owns column sx_n, k-range [kc+sx_kh*16, +16)
        {
            union { uint4 u[2]; bf16 h[16]; } T;
            const int kb = kc + sx_kh * 16;
            #pragma unroll
            for (int kk = 0; kk < 16; ++kk) {
                float v = ldf(&X[(size_t)(kb + kk) * NPIX + n0 + sx_n]);
                if constexpr (LN) v = (v - x_mu) * x_rs * lnw[kb + kk] + lnb[kb + kk];
                T.h[kk] = __float2bfloat16(v);
            }
            *(uint4*)&Xt[sx_n][sx_kh * 16] = T.u[0];
            *(uint4*)&Xt[sx_n][sx_kh * 16 + 8] = T.u[1];
        }
        __syncthreads();
        bf16x8 af[2], bfr[4];
        #pragma unroll
        for (int i = 0; i < 2; ++i)
            af[i] = *(const bf16x8*)&Wl[wm * 32 + i * 16 + lr][g * 8];
        #pragma unroll
        for (int j = 0; j < 4; ++j)
            bfr[j] = *(const bf16x8*)&Xt[wn * 64 + j * 16 + lr][g * 8];
        #pragma unroll
        for (int i = 0; i < 2; ++i)
            #pragma unroll
            for (int j = 0; j < 4; ++j)
                acc[i][j] = __builtin_amdgcn_mfma_f32_16x16x32_bf16(af[i], bfr[j], acc[i][j], 0, 0, 0);
        __syncthreads();
    }
    // epilogue
    #pragma unroll
    for (int i = 0; i < 2; ++i) {
        #pragma unroll
        for (int j = 0; j < 4; ++j) {
            #pragma unroll
            for (int r = 0; r < 4; ++r) {
                int row = m0 + wm * 32 + i * 16 + g * 4 + r;
                int col = n0 + wn * 64 + j * 16 + lr;
                float v = acc[i][j][r];
                if constexpr (RES) v += ldf(&res[(size_t)row * NPIX + col]);
                if constexpr (std::is_same_v<OT, float>)
                    out[(size_t)row * NPIX + col] = v;
                else
                    out[(size_t)row * NPIX + col] = __float2bfloat16(v);
            }
        }
    }
}

// -------------------- depthwise 3x3 (qkv), 8 px/thread, vectorized --------------------
__global__ __launch_bounds__(256) void dwconv_qkv(const bf16* __restrict__ in,
                                                  bf16* __restrict__ out,
                                                  const float* __restrict__ w9,
                                                  float* __restrict__ ssq) {
    const int bi = blockIdx.x;
    const int c = bi >> 3, rg = bi & 7;
    const int t = threadIdx.x;
    const int y = rg * 16 + (t >> 4);
    const int x0 = (t & 15) * 8;
    const bf16* ip = in + (size_t)c * NPIX;
    float w[9];
    #pragma unroll
    for (int j = 0; j < 9; ++j) w[j] = w9[c * 9 + j];

    float acc[8] = {};
    #pragma unroll
    for (int ky = 0; ky < 3; ++ky) {
        int yy = y + ky - 1;
        if (yy < 0 || yy > 127) continue;
        const bf16* rp = ip + yy * 128 + x0;
        union { uint4 u; bf16 h[8]; } V;
        V.u = *(const uint4*)rp;
        float cb[10];
        cb[0] = (x0 > 0) ? __bfloat162float(rp[-1]) : 0.f;
        #pragma unroll
        for (int j = 0; j < 8; ++j) cb[j + 1] = __bfloat162float(V.h[j]);
        cb[9] = (x0 < 120) ? __bfloat162float(rp[8]) : 0.f;
        float w0 = w[ky * 3], w1 = w[ky * 3 + 1], w2 = w[ky * 3 + 2];
        #pragma unroll
        for (int j = 0; j < 8; ++j)
            acc[j] = fmaf(w0, cb[j], fmaf(w1, cb[j + 1], fmaf(w2, cb[j + 2], acc[j])));
    }
    union { uint4 u; bf16 h[8]; } O;
    #pragma unroll
    for (int j = 0; j < 8; ++j) O.h[j] = __float2bfloat16(acc[j]);
    *(uint4*)(out + (size_t)c * NPIX + y * 128 + x0) = O.u;

    if (c < 256) {
        float s2 = 0.f;
        #pragma unroll
        for (int j = 0; j < 8; ++j) s2 = fmaf(acc[j], acc[j], s2);
        #pragma unroll
        for (int off = 32; off; off >>= 1) s2 += __shfl_down(s2, off);
        if ((t & 63) == 0) atomicAdd(&ssq[c], s2);
    }
}

// -------------------- raw attention scores --------------------
__global__ __launch_bounds__(256) void attn_scores(const bf16* __restrict__ qkvdw,
                                                   float* __restrict__ S) {
    int h = blockIdx.x, chunk = blockIdx.y;
    int n0 = chunk * 256;
    __shared__ float ql[16][260], kl[16][260];
    int t = threadIdx.x;
    int row = t >> 4, c0 = (t & 15) * 16;
    const bf16* qp = qkvdw + (size_t)(h * 16 + row) * NPIX + n0 + c0;
    const bf16* kp = qkvdw + (size_t)(128 + h * 16 + row) * NPIX + n0 + c0;
    union { uint4 u; bf16 hh[8]; } Q0, Q1, K0, K1;
    Q0.u = *(const uint4*)qp; Q1.u = *(const uint4*)(qp + 8);
    K0.u = *(const uint4*)kp; K1.u = *(const uint4*)(kp + 8);
    #pragma unroll
    for (int j = 0; j < 8; ++j) {
        ql[row][c0 + j] = __bfloat162float(Q0.hh[j]);
        ql[row][c0 + 8 + j] = __bfloat162float(Q1.hh[j]);
        kl[row][c0 + j] = __bfloat162float(K0.hh[j]);
        kl[row][c0 + 8 + j] = __bfloat162float(K1.hh[j]);
    }
    __syncthreads();
    int d = t >> 4, e = t & 15;
    float acc = 0.f;
    #pragma unroll 4
    for (int i = 0; i < 256; i += 4) {
        float4 a = *(const float4*)&ql[d][i];
        float4 b = *(const float4*)&kl[e][i];
        acc = fmaf(a.x, b.x, acc); acc = fmaf(a.y, b.y, acc);
        acc = fmaf(a.z, b.z, acc); acc = fmaf(a.w, b.w, acc);
    }
    atomicAdd(&S[(h * 16 + d) * 16 + e], acc);
}

// -------------------- softmax + W_eff = wo . blockdiag(attn), bf16 out ----------------
__global__ __launch_bounds__(256) void softmax_weff(const float* __restrict__ S,
                                                    const float* __restrict__ ssq,
                                                    const float* __restrict__ temp,
                                                    const float* __restrict__ wo,
                                                    bf16* __restrict__ Weffb) {
    __shared__ float at[2048];
    __shared__ float rn[256];
    int t = threadIdx.x;
    rn[t] = 1.f / fmaxf(sqrtf(ssq[t]), 1e-12f);
    __syncthreads();
    for (int i = t; i < 2048; i += 256) {
        int hd = i >> 4, e = i & 15, h = hd >> 4;
        at[i] = S[i] * rn[hd] * rn[128 + h * 16 + e] * temp[h];
    }
    __syncthreads();
    if (t < 128) {
        float mx = -1e30f;
        for (int e = 0; e < 16; ++e) mx = fmaxf(mx, at[t * 16 + e]);
        float s = 0.f;
        for (int e = 0; e < 16; ++e) { float v = expf(at[t * 16 + e] - mx); at[t * 16 + e] = v; s += v; }
        float inv = 1.f / s;
        for (int e = 0; e < 16; ++e) at[t * 16 + e] *= inv;
    }
    __syncthreads();
    int o = t >> 1, half = t & 1;
    for (int j = 0; j < 64; ++j) {
        int col = half * 64 + j;
        int h16 = col & ~15, e = col & 15;
        float s = 0.f;
        #pragma unroll
        for (int dd = 0; dd < 16; ++dd)
            s = fmaf(wo[o * 128 + h16 + dd], at[(h16 + dd) * 16 + e], s);
        Weffb[o * 128 + col] = __float2bfloat16(s);
    }
}

// -------------------- FFN depthwise 3x3 + GEGLU, 8 px/thread --------------------
__global__ __launch_bounds__(256) void geglu_dw(const bf16* __restrict__ g,
                                                bf16* __restrict__ y,
                                                const float* __restrict__ dww) {
    const int bi = blockIdx.x;
    const int c = bi >> 3, rg = bi & 7;
    const int t = threadIdx.x;
    const int yr = rg * 16 + (t >> 4);
    const int x0 = (t & 15) * 8;
    const bf16* g1 = g + (size_t)c * NPIX;
    const bf16* g2 = g + (size_t)(c + 512) * NPIX;
    float w1[9], w2[9];
    #pragma unroll
    for (int j = 0; j < 9; ++j) { w1[j] = dww[c * 9 + j]; w2[j] = dww[(c + 512) * 9 + j]; }

    float a1[8] = {}, a2[8] = {};
    #pragma unroll
    for (int ky = 0; ky < 3; ++ky) {
        int yy = yr + ky - 1;
        if (yy < 0 || yy > 127) continue;
        const bf16* r1 = g1 + yy * 128 + x0;
        const bf16* r2 = g2 + yy * 128 + x0;
        union { uint4 u; bf16 h[8]; } V1, V2;
        V1.u = *(const uint4*)r1;
        V2.u = *(const uint4*)r2;
        float c1[10], c2[10];
        c1[0] = (x0 > 0) ? __bfloat162float(r1[-1]) : 0.f;
        c2[0] = (x0 > 0) ? __bfloat162float(r2[-1]) : 0.f;
        #pragma unroll
        for (int j = 0; j < 8; ++j) {
            c1[j + 1] = __bfloat162float(V1.h[j]);
            c2[j + 1] = __bfloat162float(V2.h[j]);
        }
        c1[9] = (x0 < 120) ? __bfloat162float(r1[8]) : 0.f;
        c2[9] = (x0 < 120) ? __bfloat162float(r2[8]) : 0.f;
        float u0 = w1[ky * 3], u1 = w1[ky * 3 + 1], u2 = w1[ky * 3 + 2];
        float v0 = w2[ky * 3], v1 = w2[ky * 3 + 1], v2 = w2[ky * 3 + 2];
        #pragma unroll
        for (int j = 0; j < 8; ++j) {
            a1[j] = fmaf(u0, c1[j], fmaf(u1, c1[j + 1], fmaf(u2, c1[j + 2], a1[j])));
            a2[j] = fmaf(v0, c2[j], fmaf(v1, c2[j + 1], fmaf(v2, c2[j + 2], a2[j])));
        }
    }
    union { uint4 u; bf16 h[8]; } O;
    #pragma unroll
    for (int j = 0; j < 8; ++j) {
        float gelu = 0.5f * a1[j] * (1.f + erff(a1[j] * 0.70710678118f));
        O.h[j] = __float2bfloat16(gelu * a2[j]);
    }
    *(uint4*)(y + (size_t)c * NPIX + yr * 128 + x0) = O.u;
}

// ==================== host ====================
extern "C" void kernel_launch(void* const* d_in, const int* in_sizes, int n_in,
                              void* d_out, int out_size, void* d_ws, size_t ws_size,
                              hipStream_t stream) {
    const float* x    = (const float*)d_in[0];
    const float* ln1w = (const float*)d_in[1];
    const float* ln1b = (const float*)d_in[2];
    const float* wq   = (const float*)d_in[3];
    const float* wk   = (const float*)d_in[4];
    const float* wv   = (const float*)d_in[5];
    const float* dwq  = (const float*)d_in[6];
    const float* dwk  = (const float*)d_in[7];
    const float* dwv  = (const float*)d_in[8];
    const float* temp = (const float*)d_in[9];
    const float* wo   = (const float*)d_in[10];
    const float* ln2w = (const float*)d_in[11];
    const float* ln2b = (const float*)d_in[12];
    const float* w_in = (const float*)d_in[13];
    const float* dwf  = (const float*)d_in[14];
    const float* wout = (const float*)d_in[15];
    float* out = (float*)d_out;
    char* ws = (char*)d_ws;

    float* mu    = (float*)(ws + OFF_MU);
    float* rstd  = (float*)(ws + OFF_RSTD);
    float* mu2   = (float*)(ws + OFF_MU2);
    float* rstd2 = (float*)(ws + OFF_RSTD2);
    float* ssq   = (float*)(ws + OFF_SSQ);
    float* S     = (float*)(ws + OFF_S);
    float* dwp   = (float*)(ws + OFF_DWP);
    bf16*  Wqkvb = (bf16*)(ws + OFF_WQKVB);
    bf16*  winb  = (bf16*)(ws + OFF_WINB);
    bf16*  woutb = (bf16*)(ws + OFF_WOUTB);
    bf16*  Weffb = (bf16*)(ws + OFF_WEFFB);
    bf16*  x2b   = (bf16*)(ws + OFF_X2B);
    bf16*  qkv   = (bf16*)(ws + OFF_QKV);
    bf16*  qkvdw = (bf16*)(ws + OFF_QKVDW);
    bf16*  g     = (bf16*)(ws + OFF_G);
    bf16*  y     = (bf16*)(ws + OFF_Y);

    hipMemsetAsync(ws + OFF_SSQ, 0, 73728, stream);  // ssq + S
    pack_w<<<512, 256, 0, stream>>>(wq, wk, wv, dwq, dwk, dwv, w_in, wout,
                                    Wqkvb, dwp, winb, woutb);

    for (int b = 0; b < 8; ++b) {
        const float* xb = x + (size_t)b * CDIM * NPIX;
        float* mu_b = mu + b * NPIX;
        float* rstd_b = rstd + b * NPIX;
        float* ssq_b = ssq + b * 256;
        float* S_b = S + b * 2048;
        float* out_b = out + (size_t)b * CDIM * NPIX;

        ln_stats<float><<<64, 256, 0, stream>>>(xb, mu_b, rstd_b);
        // qkv = Wqkv @ LN1(x)
        gemm_mfma<float, bf16, float, true, false><<<dim3(6, 128), 256, 0, stream>>>(
            Wqkvb, xb, mu_b, rstd_b, ln1w, ln1b, nullptr, qkv, 128);
        dwconv_qkv<<<384 * 8, 256, 0, stream>>>(qkv, qkvdw, dwp, ssq_b);
        attn_scores<<<dim3(8, 64), 256, 0, stream>>>(qkvdw, S_b);
        softmax_weff<<<1, 256, 0, stream>>>(S_b, ssq_b, temp, wo, Weffb);
        // x2 = x + W_eff @ v
        gemm_mfma<bf16, bf16, float, false, true><<<dim3(2, 128), 256, 0, stream>>>(
            Weffb, qkvdw + (size_t)256 * NPIX, nullptr, nullptr, nullptr, nullptr,
            xb, x2b, 128);
        ln_stats<bf16><<<64, 256, 0, stream>>>(x2b, mu2, rstd2);
        // g = w_in @ LN2(x2)
        gemm_mfma<bf16, bf16, float, true, false><<<dim3(16, 128), 256, 0, stream>>>(
            winb, x2b, mu2, rstd2, ln2w, ln2b, nullptr, g, 128);
        geglu_dw<<<512 * 8, 256, 0, stream>>>(g, y, dwf);
        // out = x2 + w_out @ y
        gemm_mfma<bf16, float, bf16, false, true><<<dim3(2, 128), 256, 0, stream>>>(
            woutb, y, nullptr, nullptr, nullptr, nullptr, x2b, out_b, 512);
    }
    (void)in_sizes; (void)n_in; (void)out_size; (void)ws_size;
}

// Round 7
// 872.776 us; speedup vs baseline: 5.0689x; 1.7226x over previous
//
#include <hip/hip_runtime.h>
#include <hip/hip_bf16.h>
#include <type_traits>

using bf16 = __hip_bfloat16;
using f32x4  = __attribute__((ext_vector_type(4))) float;
using bf16x8 = __attribute__((ext_vector_type(8))) short;

constexpr int NPIX = 16384;   // pixels per batch (128*128)
constexpr int CDIM = 128;

// ---- workspace offsets (bytes); ws_size = 256 MiB (measured from harness poison) ----
constexpr size_t OFF_MU    = 0;          // 8*16384 f32
constexpr size_t OFF_RSTD  = 524288;     // 8*16384 f32
constexpr size_t OFF_MU2   = 1048576;    // 8*16384 f32
constexpr size_t OFF_RSTD2 = 1572864;    // 8*16384 f32
constexpr size_t OFF_SSQ   = 2097152;    // 8*256 f32
constexpr size_t OFF_S     = 2105344;    // 8*2048 f32
constexpr size_t OFF_DWP   = 2170880;    // 384*9 f32
constexpr size_t OFF_WQKVB = 2184704;    // 384*128 bf16
constexpr size_t OFF_WINB  = 2283008;    // 1024*128 bf16
constexpr size_t OFF_WOUTB = 2545152;    // 128*512 bf16
constexpr size_t OFF_WEFFB = 2676224;    // 8*128*128 bf16
constexpr size_t OFF_X2B   = 2938368;    // 8*128*16384 bf16 (33.55 MB)
constexpr size_t OFF_QKV   = 36492800;   // 8*384*16384 bf16 (100.7 MB)
constexpr size_t OFF_QKVDW = 137156096;  // 8*384*16384 bf16 (100.7 MB) -> ends 237819392
// Phase B overlays (qkv/qkvdw dead): 4 batches per group
constexpr size_t OFF_G     = 36492800;   // 4*1024*16384 bf16 (134.2 MB)
constexpr size_t OFF_Y     = 170710528;  // 4*512*16384 bf16 (67.1 MB) -> ends 237819392
// max used 237.8 MB < 256 MiB

__device__ inline float ldf(const float* p) { return *p; }
__device__ inline float ldf(const bf16* p) { return __bfloat162float(*p); }

// -------------------- pack weights to bf16 --------------------
__global__ void pack_w(const float* __restrict__ wq, const float* __restrict__ wk,
                       const float* __restrict__ wv, const float* __restrict__ dwq,
                       const float* __restrict__ dwk, const float* __restrict__ dwv,
                       const float* __restrict__ w_in, const float* __restrict__ wout,
                       bf16* __restrict__ Wqkvb, float* __restrict__ dwp,
                       bf16* __restrict__ winb, bf16* __restrict__ woutb) {
    int i = blockIdx.x * 256 + threadIdx.x;   // grid 512 -> 131072
    if (i < 384 * 128) {
        int r = i >> 7, c = i & 127;
        float v = (r < 128) ? wq[r * 128 + c] : (r < 256) ? wk[(r - 128) * 128 + c]
                                                          : wv[(r - 256) * 128 + c];
        Wqkvb[i] = __float2bfloat16(v);
    }
    if (i < 384 * 9) {
        int r = i / 9, j = i % 9;
        dwp[i] = (r < 128) ? dwq[r * 9 + j] : (r < 256) ? dwk[(r - 128) * 9 + j]
                                                        : dwv[(r - 256) * 9 + j];
    }
    if (i < 1024 * 128) winb[i] = __float2bfloat16(w_in[i]);
    if (i < 128 * 512)  woutb[i] = __float2bfloat16(wout[i]);
}

// -------------------- LayerNorm stats, batched over blockIdx.y --------------------
template <typename XT>
__global__ __launch_bounds__(256) void ln_stats(const XT* __restrict__ X, size_t xBs,
                                                float* __restrict__ mu,
                                                float* __restrict__ rstd) {
    const int b = blockIdx.y;
    const XT* Xb = X + (size_t)b * xBs;
    int n = blockIdx.x * 256 + threadIdx.x;
    float s = 0.f, s2 = 0.f;
    for (int c = 0; c < CDIM; ++c) {
        float v = ldf(&Xb[(size_t)c * NPIX + n]);
        s += v; s2 += v * v;
    }
    float m = s * (1.f / CDIM);
    float var = s2 * (1.f / CDIM) - m * m;
    mu[b * NPIX + n] = m;
    rstd[b * NPIX + n] = rsqrtf(var + 1e-5f);
}

// ---------------- MFMA GEMM, batched over blockIdx.z ----------
// out[m,n] = sum_k W[m,k]*X[k,n] (+res, +LN-on-X). tile 64M x 128N, K-step 32.
// A/B frag k-map identical (bijection cancels); C/D map HW-verified (m89).
template <typename XT, typename OT, typename RT, bool LN, bool RES>
__global__ __launch_bounds__(256) void gemm_mfma(
    const bf16* __restrict__ Wb0, int wBs, const XT* __restrict__ X0, size_t xBs,
    const float* __restrict__ mu0, const float* __restrict__ rstd0,
    const float* __restrict__ lnw, const float* __restrict__ lnb,
    const RT* __restrict__ res0, size_t rBs, OT* __restrict__ out0, size_t oBs, int K) {
    __shared__ bf16 Wl[64][40];    // [m][k], row stride 80B (16B-aligned)
    __shared__ bf16 Xt[128][40];   // [n][k] transposed
    const int t = threadIdx.x;
    const int b = blockIdx.z;
    const bf16* Wb = Wb0 + (size_t)b * wBs;
    const XT* X = X0 + (size_t)b * xBs;
    const RT* res = RES ? res0 + (size_t)b * rBs : nullptr;
    OT* out = out0 + (size_t)b * oBs;
    const float* mu = LN ? mu0 + (size_t)b * NPIX : nullptr;
    const float* rstd = LN ? rstd0 + (size_t)b * NPIX : nullptr;

    const int lane = t & 63, wave = t >> 6;
    const int wm = wave >> 1, wn = wave & 1;
    const int g = lane >> 4, lr = lane & 15;
    const int m0 = blockIdx.x * 64, n0 = blockIdx.y * 128;

    const int sw_row = t >> 2, sw_k8 = (t & 3) * 8;  // W staging: 8 bf16 per thread
    const int sx_n = t & 127, sx_kh = t >> 7;        // X staging: 16 k's for one n

    float x_mu = 0.f, x_rs = 0.f;
    if constexpr (LN) { x_mu = mu[n0 + sx_n]; x_rs = rstd[n0 + sx_n]; }

    f32x4 acc[2][4];
    #pragma unroll
    for (int i = 0; i < 2; ++i)
        #pragma unroll
        for (int j = 0; j < 4; ++j)
            acc[i][j] = (f32x4){0.f, 0.f, 0.f, 0.f};

    for (int kc = 0; kc < K; kc += 32) {
        uint4 wv = *(const uint4*)(Wb + (size_t)(m0 + sw_row) * K + kc + sw_k8);
        *(uint4*)&Wl[sw_row][sw_k8] = wv;
        {
            union { uint4 u[2]; bf16 h[16]; } T;
            const int kb = kc + sx_kh * 16;
            #pragma unroll
            for (int kk = 0; kk < 16; ++kk) {
                float v = ldf(&X[(size_t)(kb + kk) * NPIX + n0 + sx_n]);
                if constexpr (LN) v = (v - x_mu) * x_rs * lnw[kb + kk] + lnb[kb + kk];
                T.h[kk] = __float2bfloat16(v);
            }
            *(uint4*)&Xt[sx_n][sx_kh * 16] = T.u[0];
            *(uint4*)&Xt[sx_n][sx_kh * 16 + 8] = T.u[1];
        }
        __syncthreads();
        bf16x8 af[2], bfr[4];
        #pragma unroll
        for (int i = 0; i < 2; ++i)
            af[i] = *(const bf16x8*)&Wl[wm * 32 + i * 16 + lr][g * 8];
        #pragma unroll
        for (int j = 0; j < 4; ++j)
            bfr[j] = *(const bf16x8*)&Xt[wn * 64 + j * 16 + lr][g * 8];
        #pragma unroll
        for (int i = 0; i < 2; ++i)
            #pragma unroll
            for (int j = 0; j < 4; ++j)
                acc[i][j] = __builtin_amdgcn_mfma_f32_16x16x32_bf16(af[i], bfr[j], acc[i][j], 0, 0, 0);
        __syncthreads();
    }
    #pragma unroll
    for (int i = 0; i < 2; ++i) {
        #pragma unroll
        for (int j = 0; j < 4; ++j) {
            #pragma unroll
            for (int r = 0; r < 4; ++r) {
                int row = m0 + wm * 32 + i * 16 + g * 4 + r;
                int col = n0 + wn * 64 + j * 16 + lr;
                float v = acc[i][j][r];
                if constexpr (RES) v += ldf(&res[(size_t)row * NPIX + col]);
                if constexpr (std::is_same_v<OT, float>)
                    out[(size_t)row * NPIX + col] = v;
                else
                    out[(size_t)row * NPIX + col] = __float2bfloat16(v);
            }
        }
    }
}

// -------------------- depthwise 3x3 (qkv), 8 px/thread, batched z --------------------
__global__ __launch_bounds__(256) void dwconv_qkv(const bf16* __restrict__ in0,
                                                  bf16* __restrict__ out0,
                                                  const float* __restrict__ w9,
                                                  float* __restrict__ ssq0) {
    const int b = blockIdx.z;
    const bf16* in = in0 + (size_t)b * 384 * NPIX;
    bf16* out = out0 + (size_t)b * 384 * NPIX;
    float* ssq = ssq0 + b * 256;
    const int bi = blockIdx.x;
    const int c = bi >> 3, rg = bi & 7;
    const int t = threadIdx.x;
    const int y = rg * 16 + (t >> 4);
    const int x0 = (t & 15) * 8;
    const bf16* ip = in + (size_t)c * NPIX;
    float w[9];
    #pragma unroll
    for (int j = 0; j < 9; ++j) w[j] = w9[c * 9 + j];

    float acc[8] = {};
    #pragma unroll
    for (int ky = 0; ky < 3; ++ky) {
        int yy = y + ky - 1;
        if (yy < 0 || yy > 127) continue;
        const bf16* rp = ip + yy * 128 + x0;
        union { uint4 u; bf16 h[8]; } V;
        V.u = *(const uint4*)rp;
        float cb[10];
        cb[0] = (x0 > 0) ? __bfloat162float(rp[-1]) : 0.f;
        #pragma unroll
        for (int j = 0; j < 8; ++j) cb[j + 1] = __bfloat162float(V.h[j]);
        cb[9] = (x0 < 120) ? __bfloat162float(rp[8]) : 0.f;
        float w0 = w[ky * 3], w1 = w[ky * 3 + 1], w2 = w[ky * 3 + 2];
        #pragma unroll
        for (int j = 0; j < 8; ++j)
            acc[j] = fmaf(w0, cb[j], fmaf(w1, cb[j + 1], fmaf(w2, cb[j + 2], acc[j])));
    }
    union { uint4 u; bf16 h[8]; } O;
    #pragma unroll
    for (int j = 0; j < 8; ++j) O.h[j] = __float2bfloat16(acc[j]);
    *(uint4*)(out + (size_t)c * NPIX + y * 128 + x0) = O.u;

    if (c < 256) {
        float s2 = 0.f;
        #pragma unroll
        for (int j = 0; j < 8; ++j) s2 = fmaf(acc[j], acc[j], s2);
        #pragma unroll
        for (int off = 32; off; off >>= 1) s2 += __shfl_down(s2, off);
        if ((t & 63) == 0) atomicAdd(&ssq[c], s2);
    }
}

// -------------------- raw attention scores, batched z --------------------
__global__ __launch_bounds__(256) void attn_scores(const bf16* __restrict__ qkvdw0,
                                                   float* __restrict__ S0) {
    const int b = blockIdx.z;
    const bf16* qkvdw = qkvdw0 + (size_t)b * 384 * NPIX;
    float* S = S0 + b * 2048;
    int h = blockIdx.x, chunk = blockIdx.y;
    int n0 = chunk * 256;
    __shared__ float ql[16][260], kl[16][260];
    int t = threadIdx.x;
    int row = t >> 4, c0 = (t & 15) * 16;
    const bf16* qp = qkvdw + (size_t)(h * 16 + row) * NPIX + n0 + c0;
    const bf16* kp = qkvdw + (size_t)(128 + h * 16 + row) * NPIX + n0 + c0;
    union { uint4 u; bf16 hh[8]; } Q0, Q1, K0, K1;
    Q0.u = *(const uint4*)qp; Q1.u = *(const uint4*)(qp + 8);
    K0.u = *(const uint4*)kp; K1.u = *(const uint4*)(kp + 8);
    #pragma unroll
    for (int j = 0; j < 8; ++j) {
        ql[row][c0 + j] = __bfloat162float(Q0.hh[j]);
        ql[row][c0 + 8 + j] = __bfloat162float(Q1.hh[j]);
        kl[row][c0 + j] = __bfloat162float(K0.hh[j]);
        kl[row][c0 + 8 + j] = __bfloat162float(K1.hh[j]);
    }
    __syncthreads();
    int d = t >> 4, e = t & 15;
    float acc = 0.f;
    #pragma unroll 4
    for (int i = 0; i < 256; i += 4) {
        float4 a = *(const float4*)&ql[d][i];
        float4 bv = *(const float4*)&kl[e][i];
        acc = fmaf(a.x, bv.x, acc); acc = fmaf(a.y, bv.y, acc);
        acc = fmaf(a.z, bv.z, acc); acc = fmaf(a.w, bv.w, acc);
    }
    atomicAdd(&S[(h * 16 + d) * 16 + e], acc);
}

// -------------------- softmax + W_eff, one block per batch --------------------
__global__ __launch_bounds__(256) void softmax_weff(const float* __restrict__ S0,
                                                    const float* __restrict__ ssq0,
                                                    const float* __restrict__ temp,
                                                    const float* __restrict__ wo,
                                                    bf16* __restrict__ Weffb0) {
    const int b = blockIdx.x;
    const float* S = S0 + b * 2048;
    const float* ssq = ssq0 + b * 256;
    bf16* Weffb = Weffb0 + b * 16384;
    __shared__ float at[2048];
    __shared__ float rn[256];
    int t = threadIdx.x;
    rn[t] = 1.f / fmaxf(sqrtf(ssq[t]), 1e-12f);
    __syncthreads();
    for (int i = t; i < 2048; i += 256) {
        int hd = i >> 4, e = i & 15, h = hd >> 4;
        at[i] = S[i] * rn[hd] * rn[128 + h * 16 + e] * temp[h];
    }
    __syncthreads();
    if (t < 128) {
        float mx = -1e30f;
        for (int e = 0; e < 16; ++e) mx = fmaxf(mx, at[t * 16 + e]);
        float s = 0.f;
        for (int e = 0; e < 16; ++e) { float v = expf(at[t * 16 + e] - mx); at[t * 16 + e] = v; s += v; }
        float inv = 1.f / s;
        for (int e = 0; e < 16; ++e) at[t * 16 + e] *= inv;
    }
    __syncthreads();
    int o = t >> 1, half = t & 1;
    for (int j = 0; j < 64; ++j) {
        int col = half * 64 + j;
        int h16 = col & ~15, e = col & 15;
        float s = 0.f;
        #pragma unroll
        for (int dd = 0; dd < 16; ++dd)
            s = fmaf(wo[o * 128 + h16 + dd], at[(h16 + dd) * 16 + e], s);
        Weffb[o * 128 + col] = __float2bfloat16(s);
    }
}

// -------------------- FFN depthwise 3x3 + GEGLU, 8 px/thread, batched z ----------------
__global__ __launch_bounds__(256) void geglu_dw(const bf16* __restrict__ g0,
                                                bf16* __restrict__ y0,
                                                const float* __restrict__ dww) {
    const int b = blockIdx.z;
    const bf16* g = g0 + (size_t)b * 1024 * NPIX;
    bf16* y = y0 + (size_t)b * 512 * NPIX;
    const int bi = blockIdx.x;
    const int c = bi >> 3, rg = bi & 7;
    const int t = threadIdx.x;
    const int yr = rg * 16 + (t >> 4);
    const int x0 = (t & 15) * 8;
    const bf16* g1 = g + (size_t)c * NPIX;
    const bf16* g2 = g + (size_t)(c + 512) * NPIX;
    float w1[9], w2[9];
    #pragma unroll
    for (int j = 0; j < 9; ++j) { w1[j] = dww[c * 9 + j]; w2[j] = dww[(c + 512) * 9 + j]; }

    float a1[8] = {}, a2[8] = {};
    #pragma unroll
    for (int ky = 0; ky < 3; ++ky) {
        int yy = yr + ky - 1;
        if (yy < 0 || yy > 127) continue;
        const bf16* r1 = g1 + yy * 128 + x0;
        const bf16* r2 = g2 + yy * 128 + x0;
        union { uint4 u; bf16 h[8]; } V1, V2;
        V1.u = *(const uint4*)r1;
        V2.u = *(const uint4*)r2;
        float c1[10], c2[10];
        c1[0] = (x0 > 0) ? __bfloat162float(r1[-1]) : 0.f;
        c2[0] = (x0 > 0) ? __bfloat162float(r2[-1]) : 0.f;
        #pragma unroll
        for (int j = 0; j < 8; ++j) {
            c1[j + 1] = __bfloat162float(V1.h[j]);
            c2[j + 1] = __bfloat162float(V2.h[j]);
        }
        c1[9] = (x0 < 120) ? __bfloat162float(r1[8]) : 0.f;
        c2[9] = (x0 < 120) ? __bfloat162float(r2[8]) : 0.f;
        float u0 = w1[ky * 3], u1 = w1[ky * 3 + 1], u2 = w1[ky * 3 + 2];
        float v0 = w2[ky * 3], v1 = w2[ky * 3 + 1], v2 = w2[ky * 3 + 2];
        #pragma unroll
        for (int j = 0; j < 8; ++j) {
            a1[j] = fmaf(u0, c1[j], fmaf(u1, c1[j + 1], fmaf(u2, c1[j + 2], a1[j])));
            a2[j] = fmaf(v0, c2[j], fmaf(v1, c2[j + 1], fmaf(v2, c2[j + 2], a2[j])));
        }
    }
    union { uint4 u; bf16 h[8]; } O;
    #pragma unroll
    for (int j = 0; j < 8; ++j) {
        float gelu = 0.5f * a1[j] * (1.f + erff(a1[j] * 0.70710678118f));
        O.h[j] = __float2bfloat16(gelu * a2[j]);
    }
    *(uint4*)(y + (size_t)c * NPIX + yr * 128 + x0) = O.u;
}

// ==================== host ====================
extern "C" void kernel_launch(void* const* d_in, const int* in_sizes, int n_in,
                              void* d_out, int out_size, void* d_ws, size_t ws_size,
                              hipStream_t stream) {
    const float* x    = (const float*)d_in[0];
    const float* ln1w = (const float*)d_in[1];
    const float* ln1b = (const float*)d_in[2];
    const float* wq   = (const float*)d_in[3];
    const float* wk   = (const float*)d_in[4];
    const float* wv   = (const float*)d_in[5];
    const float* dwq  = (const float*)d_in[6];
    const float* dwk  = (const float*)d_in[7];
    const float* dwv  = (const float*)d_in[8];
    const float* temp = (const float*)d_in[9];
    const float* wo   = (const float*)d_in[10];
    const float* ln2w = (const float*)d_in[11];
    const float* ln2b = (const float*)d_in[12];
    const float* w_in = (const float*)d_in[13];
    const float* dwf  = (const float*)d_in[14];
    const float* wout = (const float*)d_in[15];
    float* out = (float*)d_out;
    char* ws = (char*)d_ws;

    float* mu    = (float*)(ws + OFF_MU);
    float* rstd  = (float*)(ws + OFF_RSTD);
    float* mu2   = (float*)(ws + OFF_MU2);
    float* rstd2 = (float*)(ws + OFF_RSTD2);
    float* ssq   = (float*)(ws + OFF_SSQ);
    float* S     = (float*)(ws + OFF_S);
    float* dwp   = (float*)(ws + OFF_DWP);
    bf16*  Wqkvb = (bf16*)(ws + OFF_WQKVB);
    bf16*  winb  = (bf16*)(ws + OFF_WINB);
    bf16*  woutb = (bf16*)(ws + OFF_WOUTB);
    bf16*  Weffb = (bf16*)(ws + OFF_WEFFB);
    bf16*  x2b   = (bf16*)(ws + OFF_X2B);
    bf16*  qkv   = (bf16*)(ws + OFF_QKV);
    bf16*  qkvdw = (bf16*)(ws + OFF_QKVDW);
    bf16*  g     = (bf16*)(ws + OFF_G);
    bf16*  y     = (bf16*)(ws + OFF_Y);

    const size_t XB = (size_t)CDIM * NPIX;     // per-batch x / x2b stride
    const size_t QB = (size_t)384 * NPIX;      // per-batch qkv stride

    hipMemsetAsync(ws + OFF_SSQ, 0, 73728, stream);  // ssq + S (all batches)
    pack_w<<<512, 256, 0, stream>>>(wq, wk, wv, dwq, dwk, dwv, w_in, wout,
                                    Wqkvb, dwp, winb, woutb);

    // ---- Phase A: attention, all 8 batches ----
    ln_stats<float><<<dim3(64, 8), 256, 0, stream>>>(x, XB, mu, rstd);
    gemm_mfma<float, bf16, float, true, false><<<dim3(6, 128, 8), 256, 0, stream>>>(
        Wqkvb, 0, x, XB, mu, rstd, ln1w, ln1b, nullptr, 0, qkv, QB, 128);
    dwconv_qkv<<<dim3(384 * 8, 1, 8), 256, 0, stream>>>(qkv, qkvdw, dwp, ssq);
    attn_scores<<<dim3(8, 64, 8), 256, 0, stream>>>(qkvdw, S);
    softmax_weff<<<8, 256, 0, stream>>>(S, ssq, temp, wo, Weffb);
    gemm_mfma<bf16, bf16, float, false, true><<<dim3(2, 128, 8), 256, 0, stream>>>(
        Weffb, 16384, qkvdw + (size_t)256 * NPIX, QB, nullptr, nullptr, nullptr, nullptr,
        x, XB, x2b, XB, 128);
    ln_stats<bf16><<<dim3(64, 8), 256, 0, stream>>>(x2b, XB, mu2, rstd2);

    // ---- Phase B: FFN, two groups of 4 batches (g/y overlay dead qkv/qkvdw) ----
    for (int grp = 0; grp < 2; ++grp) {
        const bf16* x2g = x2b + (size_t)grp * 4 * XB;
        gemm_mfma<bf16, bf16, float, true, false><<<dim3(16, 128, 4), 256, 0, stream>>>(
            winb, 0, x2g, XB, mu2 + (size_t)grp * 4 * NPIX, rstd2 + (size_t)grp * 4 * NPIX,
            ln2w, ln2b, nullptr, 0, g, (size_t)1024 * NPIX, 128);
        geglu_dw<<<dim3(512 * 8, 1, 4), 256, 0, stream>>>(g, y, dwf);
        gemm_mfma<bf16, float, bf16, false, true><<<dim3(2, 128, 4), 256, 0, stream>>>(
            woutb, 0, y, (size_t)512 * NPIX, nullptr, nullptr, nullptr, nullptr,
            x2g, XB, out + (size_t)grp * 4 * XB, XB, 512);
    }
    (void)in_sizes; (void)n_in; (void)out_size; (void)ws_size;
}

// Round 10
// 692.735 us; speedup vs baseline: 6.3863x; 1.2599x over previous
//
#include <hip/hip_runtime.h>
#include <hip/hip_bf16.h>
#include <type_traits>

using bf16 = __hip_bfloat16;
using f32x4  = __attribute__((ext_vector_type(4))) float;
using bf16x8 = __attribute__((ext_vector_type(8))) short;

constexpr int NPIX = 16384;   // pixels per batch (128*128)
constexpr int CDIM = 128;

// ---- workspace offsets (bytes); ws_size = 256 MiB ----
constexpr size_t OFF_MU    = 0;          // 8*16384 f32
constexpr size_t OFF_RSTD  = 524288;     // 8*16384 f32
constexpr size_t OFF_MU2   = 1048576;    // 8*16384 f32
constexpr size_t OFF_RSTD2 = 1572864;    // 8*16384 f32
constexpr size_t OFF_SSQ   = 2097152;    // 8*256 f32
constexpr size_t OFF_S     = 2105344;    // 8*2048 f32
constexpr size_t OFF_DWP   = 2170880;    // 384*9 f32
constexpr size_t OFF_WQKVB = 2184704;    // 384*128 bf16
constexpr size_t OFF_WINB  = 2283008;    // 1024*128 bf16
constexpr size_t OFF_WOUTB = 2545152;    // 128*512 bf16
constexpr size_t OFF_WEFFB = 2676224;    // 8*128*128 bf16
constexpr size_t OFF_X2B   = 2938368;    // 8*128*16384 bf16 (33.55 MB)
constexpr size_t OFF_QKV   = 36492800;   // 8*384*16384 bf16 (100.7 MB)
constexpr size_t OFF_QKVDW = 137156096;  // 8*384*16384 bf16 (100.7 MB) -> ends 237819392
// Phase B overlays (qkv/qkvdw dead): 4 batches per group
constexpr size_t OFF_G     = 36492800;   // 4*1024*16384 bf16 (134.2 MB)
constexpr size_t OFF_Y     = 170710528;  // 4*512*16384 bf16 (67.1 MB) -> ends 237819392

__device__ inline float ldf(const float* p) { return *p; }
__device__ inline float ldf(const bf16* p) { return __bfloat162float(*p); }

// -------------------- pack weights to bf16 --------------------
__global__ void pack_w(const float* __restrict__ wq, const float* __restrict__ wk,
                       const float* __restrict__ wv, const float* __restrict__ dwq,
                       const float* __restrict__ dwk, const float* __restrict__ dwv,
                       const float* __restrict__ w_in, const float* __restrict__ wout,
                       bf16* __restrict__ Wqkvb, float* __restrict__ dwp,
                       bf16* __restrict__ winb, bf16* __restrict__ woutb) {
    int i = blockIdx.x * 256 + threadIdx.x;   // grid 512 -> 131072
    if (i < 384 * 128) {
        int r = i >> 7, c = i & 127;
        float v = (r < 128) ? wq[r * 128 + c] : (r < 256) ? wk[(r - 128) * 128 + c]
                                                          : wv[(r - 256) * 128 + c];
        Wqkvb[i] = __float2bfloat16(v);
    }
    if (i < 384 * 9) {
        int r = i / 9, j = i % 9;
        dwp[i] = (r < 128) ? dwq[r * 9 + j] : (r < 256) ? dwk[(r - 128) * 9 + j]
                                                        : dwv[(r - 256) * 9 + j];
    }
    if (i < 1024 * 128) winb[i] = __float2bfloat16(w_in[i]);
    if (i < 128 * 512)  woutb[i] = __float2bfloat16(wout[i]);
}

// -------------------- LayerNorm stats, batched over blockIdx.y --------------------
template <typename XT>
__global__ __launch_bounds__(256) void ln_stats(const XT* __restrict__ X, size_t xBs,
                                                float* __restrict__ mu,
                                                float* __restrict__ rstd) {
    const int b = blockIdx.y;
    const XT* Xb = X + (size_t)b * xBs;
    int n = blockIdx.x * 256 + threadIdx.x;
    float s = 0.f, s2 = 0.f;
    for (int c = 0; c < CDIM; ++c) {
        float v = ldf(&Xb[(size_t)c * NPIX + n]);
        s += v; s2 += v * v;
    }
    float m = s * (1.f / CDIM);
    float var = s2 * (1.f / CDIM) - m * m;
    mu[b * NPIX + n] = m;
    rstd[b * NPIX + n] = rsqrtf(var + 1e-5f);
}

// ---------------- MFMA GEMM, batched over blockIdx.z ----------
template <typename XT, typename OT, typename RT, bool LN, bool RES>
__global__ __launch_bounds__(256) void gemm_mfma(
    const bf16* __restrict__ Wb0, int wBs, const XT* __restrict__ X0, size_t xBs,
    const float* __restrict__ mu0, const float* __restrict__ rstd0,
    const float* __restrict__ lnw, const float* __restrict__ lnb,
    const RT* __restrict__ res0, size_t rBs, OT* __restrict__ out0, size_t oBs, int K) {
    __shared__ bf16 Wl[64][40];    // [m][k]
    __shared__ bf16 Xt[128][40];   // [n][k] transposed
    const int t = threadIdx.x;
    const int b = blockIdx.z;
    const bf16* Wb = Wb0 + (size_t)b * wBs;
    const XT* X = X0 + (size_t)b * xBs;
    const RT* res = RES ? res0 + (size_t)b * rBs : nullptr;
    OT* out = out0 + (size_t)b * oBs;
    const float* mu = LN ? mu0 + (size_t)b * NPIX : nullptr;
    const float* rstd = LN ? rstd0 + (size_t)b * NPIX : nullptr;

    const int lane = t & 63, wave = t >> 6;
    const int wm = wave >> 1, wn = wave & 1;
    const int g = lane >> 4, lr = lane & 15;
    const int m0 = blockIdx.x * 64, n0 = blockIdx.y * 128;

    const int sw_row = t >> 2, sw_k8 = (t & 3) * 8;
    const int sx_n = t & 127, sx_kh = t >> 7;

    float x_mu = 0.f, x_rs = 0.f;
    if constexpr (LN) { x_mu = mu[n0 + sx_n]; x_rs = rstd[n0 + sx_n]; }

    f32x4 acc[2][4];
    #pragma unroll
    for (int i = 0; i < 2; ++i)
        #pragma unroll
        for (int j = 0; j < 4; ++j)
            acc[i][j] = (f32x4){0.f, 0.f, 0.f, 0.f};

    for (int kc = 0; kc < K; kc += 32) {
        uint4 wv = *(const uint4*)(Wb + (size_t)(m0 + sw_row) * K + kc + sw_k8);
        *(uint4*)&Wl[sw_row][sw_k8] = wv;
        {
            union { uint4 u[2]; bf16 h[16]; } T;
            const int kb = kc + sx_kh * 16;
            #pragma unroll
            for (int kk = 0; kk < 16; ++kk) {
                float v = ldf(&X[(size_t)(kb + kk) * NPIX + n0 + sx_n]);
                if constexpr (LN) v = (v - x_mu) * x_rs * lnw[kb + kk] + lnb[kb + kk];
                T.h[kk] = __float2bfloat16(v);
            }
            *(uint4*)&Xt[sx_n][sx_kh * 16] = T.u[0];
            *(uint4*)&Xt[sx_n][sx_kh * 16 + 8] = T.u[1];
        }
        __syncthreads();
        bf16x8 af[2], bfr[4];
        #pragma unroll
        for (int i = 0; i < 2; ++i)
            af[i] = *(const bf16x8*)&Wl[wm * 32 + i * 16 + lr][g * 8];
        #pragma unroll
        for (int j = 0; j < 4; ++j)
            bfr[j] = *(const bf16x8*)&Xt[wn * 64 + j * 16 + lr][g * 8];
        #pragma unroll
        for (int i = 0; i < 2; ++i)
            #pragma unroll
            for (int j = 0; j < 4; ++j)
                acc[i][j] = __builtin_amdgcn_mfma_f32_16x16x32_bf16(af[i], bfr[j], acc[i][j], 0, 0, 0);
        __syncthreads();
    }
    #pragma unroll
    for (int i = 0; i < 2; ++i) {
        #pragma unroll
        for (int j = 0; j < 4; ++j) {
            #pragma unroll
            for (int r = 0; r < 4; ++r) {
                int row = m0 + wm * 32 + i * 16 + g * 4 + r;
                int col = n0 + wn * 64 + j * 16 + lr;
                float v = acc[i][j][r];
                if constexpr (RES) v += ldf(&res[(size_t)row * NPIX + col]);
                if constexpr (std::is_same_v<OT, float>)
                    out[(size_t)row * NPIX + col] = v;
                else
                    out[(size_t)row * NPIX + col] = __float2bfloat16(v);
            }
        }
    }
}

// ---------- depthwise 3x3 (qkv), 8-row strip/thread, rolling registers ----------
// grid (384 channels, 8 batches); block 256 = 16 tx (8px) x 16 ty (8 rows).
__global__ __launch_bounds__(256) void dwconv_qkv(const bf16* __restrict__ in0,
                                                  bf16* __restrict__ out0,
                                                  const float* __restrict__ w9,
                                                  float* __restrict__ ssq0) {
    const int b = blockIdx.y, c = blockIdx.x;
    const bf16* in = in0 + ((size_t)b * 384 + c) * NPIX;
    bf16* out = out0 + ((size_t)b * 384 + c) * NPIX;
    float* ssq = ssq0 + b * 256;
    const int t = threadIdx.x;
    const int lane = t & 63;
    const int tx = t & 15, ty = t >> 4;
    const int x0 = tx * 8, ybase = ty * 8;
    float w[9];
    #pragma unroll
    for (int j = 0; j < 9; ++j) w[j] = w9[c * 9 + j];

    float r[3][10];  // [slot][0]=left halo, [1..8]=px, [9]=right halo
    auto loadrow = [&](int yy, float* d) {
        union { uint4 u; bf16 h[8]; } V;
        bool ok = (yy >= 0 && yy <= 127);
        V.u = ok ? *(const uint4*)(in + yy * 128 + x0) : make_uint4(0u, 0u, 0u, 0u);
        #pragma unroll
        for (int j = 0; j < 8; ++j) d[j + 1] = __bfloat162float(V.h[j]);
        float Lv = __shfl(d[8], lane - 1, 64);
        float Rv = __shfl(d[1], lane + 1, 64);
        d[0] = (tx == 0) ? 0.f : Lv;
        d[9] = (tx == 15) ? 0.f : Rv;
    };

    loadrow(ybase - 1, r[0]);
    loadrow(ybase, r[1]);
    float s2 = 0.f;
    #pragma unroll
    for (int j = 0; j < 8; ++j) {
        loadrow(ybase + j + 1, r[(j + 2) % 3]);
        const float* rm = r[j % 3];
        const float* rc = r[(j + 1) % 3];
        const float* rp = r[(j + 2) % 3];
        union { uint4 u; bf16 h[8]; } O;
        #pragma unroll
        for (int p = 0; p < 8; ++p) {
            float a = w[0] * rm[p] + w[1] * rm[p + 1] + w[2] * rm[p + 2]
                    + w[3] * rc[p] + w[4] * rc[p + 1] + w[5] * rc[p + 2]
                    + w[6] * rp[p] + w[7] * rp[p + 1] + w[8] * rp[p + 2];
            s2 = fmaf(a, a, s2);
            O.h[p] = __float2bfloat16(a);
        }
        *(uint4*)(out + (ybase + j) * 128 + x0) = O.u;
    }
    if (c < 256) {
        #pragma unroll
        for (int off = 32; off; off >>= 1) s2 += __shfl_down(s2, off);
        if (lane == 0) atomicAdd(&ssq[c], s2);
    }
}

// -------------------- attention scores via MFMA: S[d,e] = sum_n q[d,n]k[e,n] ----------
// grid (8 heads, 8 chunks, 8 batches); block 256. NT-GEMM: both frags row-contiguous.
__global__ __launch_bounds__(256) void attn_scores(const bf16* __restrict__ qkvdw0,
                                                   float* __restrict__ S0) {
    const int b = blockIdx.z;
    const bf16* base = qkvdw0 + (size_t)b * 384 * NPIX;
    float* S = S0 + b * 2048;
    const int h = blockIdx.x;
    const int n00 = blockIdx.y * 2048;
    __shared__ bf16 ql[16][264], kl[16][264];   // pad 8 -> frag reads ~2-way (free)
    __shared__ float sacc[4][256];
    const int t = threadIdx.x;
    const int lane = t & 63, wave = t >> 6;
    const int lr = lane & 15, g = lane >> 4;
    const bf16* qbase = base + (size_t)(h * 16) * NPIX;
    const bf16* kbase = base + (size_t)(128 + h * 16) * NPIX;

    f32x4 acc = (f32x4){0.f, 0.f, 0.f, 0.f};
    for (int it = 0; it < 8; ++it) {
        const int n0 = n00 + it * 256;
        __syncthreads();   // prior-iter reads done before overwrite
        #pragma unroll
        for (int s = 0; s < 2; ++s) {
            int idx = t + s * 256;
            int row = idx >> 5, cc = (idx & 31) * 8;
            *(uint4*)&ql[row][cc] = *(const uint4*)(qbase + (size_t)row * NPIX + n0 + cc);
            *(uint4*)&kl[row][cc] = *(const uint4*)(kbase + (size_t)row * NPIX + n0 + cc);
        }
        __syncthreads();
        #pragma unroll
        for (int m = 0; m < 2; ++m) {
            const int kc = wave * 64 + m * 32 + g * 8;
            bf16x8 aq = *(const bf16x8*)&ql[lr][kc];
            bf16x8 bk = *(const bf16x8*)&kl[lr][kc];
            acc = __builtin_amdgcn_mfma_f32_16x16x32_bf16(aq, bk, acc, 0, 0, 0);
        }
    }
    #pragma unroll
    for (int r = 0; r < 4; ++r) {
        int d = g * 4 + r, e = lr;
        sacc[wave][d * 16 + e] = acc[r];
    }
    __syncthreads();
    float s = sacc[0][t] + sacc[1][t] + sacc[2][t] + sacc[3][t];
    atomicAdd(&S[h * 256 + t], s);
}

// -------------------- softmax + W_eff, one block per batch --------------------
__global__ __launch_bounds__(256) void softmax_weff(const float* __restrict__ S0,
                                                    const float* __restrict__ ssq0,
                                                    const float* __restrict__ temp,
                                                    const float* __restrict__ wo,
                                                    bf16* __restrict__ Weffb0) {
    const int b = blockIdx.x;
    const float* S = S0 + b * 2048;
    const float* ssq = ssq0 + b * 256;
    bf16* Weffb = Weffb0 + b * 16384;
    __shared__ float at[2048];
    __shared__ float rn[256];
    int t = threadIdx.x;
    rn[t] = 1.f / fmaxf(sqrtf(ssq[t]), 1e-12f);
    __syncthreads();
    for (int i = t; i < 2048; i += 256) {
        int hd = i >> 4, e = i & 15, h = hd >> 4;
        at[i] = S[i] * rn[hd] * rn[128 + h * 16 + e] * temp[h];
    }
    __syncthreads();
    if (t < 128) {
        float mx = -1e30f;
        for (int e = 0; e < 16; ++e) mx = fmaxf(mx, at[t * 16 + e]);
        float s = 0.f;
        for (int e = 0; e < 16; ++e) { float v = expf(at[t * 16 + e] - mx); at[t * 16 + e] = v; s += v; }
        float inv = 1.f / s;
        for (int e = 0; e < 16; ++e) at[t * 16 + e] *= inv;
    }
    __syncthreads();
    int o = t >> 1, half = t & 1;
    for (int j = 0; j < 64; ++j) {
        int col = half * 64 + j;
        int h16 = col & ~15, e = col & 15;
        float s = 0.f;
        #pragma unroll
        for (int dd = 0; dd < 16; ++dd)
            s = fmaf(wo[o * 128 + h16 + dd], at[(h16 + dd) * 16 + e], s);
        Weffb[o * 128 + col] = __float2bfloat16(s);
    }
}

// ---------- FFN depthwise 3x3 + GEGLU, 8-row strip/thread ----------
// grid (512 channels, 4 batches); block 256 = 16 tx x 16 ty.
__global__ __launch_bounds__(256) void geglu_dw(const bf16* __restrict__ g0,
                                                bf16* __restrict__ y0,
                                                const float* __restrict__ dww) {
    const int b = blockIdx.y, c = blockIdx.x;
    const bf16* g1 = g0 + ((size_t)b * 1024 + c) * NPIX;
    const bf16* g2 = g0 + ((size_t)b * 1024 + c + 512) * NPIX;
    bf16* y = y0 + ((size_t)b * 512 + c) * NPIX;
    const int t = threadIdx.x;
    const int lane = t & 63;
    const int tx = t & 15, ty = t >> 4;
    const int x0 = tx * 8, ybase = ty * 8;
    float w1[9], w2[9];
    #pragma unroll
    for (int j = 0; j < 9; ++j) { w1[j] = dww[c * 9 + j]; w2[j] = dww[(c + 512) * 9 + j]; }

    float ra[3][10], rb[3][10];
    auto loadrow = [&](const bf16* src, int yy, float* d) {
        union { uint4 u; bf16 h[8]; } V;
        bool ok = (yy >= 0 && yy <= 127);
        V.u = ok ? *(const uint4*)(src + yy * 128 + x0) : make_uint4(0u, 0u, 0u, 0u);
        #pragma unroll
        for (int j = 0; j < 8; ++j) d[j + 1] = __bfloat162float(V.h[j]);
        float Lv = __shfl(d[8], lane - 1, 64);
        float Rv = __shfl(d[1], lane + 1, 64);
        d[0] = (tx == 0) ? 0.f : Lv;
        d[9] = (tx == 15) ? 0.f : Rv;
    };

    loadrow(g1, ybase - 1, ra[0]); loadrow(g1, ybase, ra[1]);
    loadrow(g2, ybase - 1, rb[0]); loadrow(g2, ybase, rb[1]);
    #pragma unroll
    for (int j = 0; j < 8; ++j) {
        loadrow(g1, ybase + j + 1, ra[(j + 2) % 3]);
        loadrow(g2, ybase + j + 1, rb[(j + 2) % 3]);
        const float* am = ra[j % 3]; const float* ac = ra[(j + 1) % 3]; const float* ap = ra[(j + 2) % 3];
        const float* bm = rb[j % 3]; const float* bc = rb[(j + 1) % 3]; const float* bp = rb[(j + 2) % 3];
        union { uint4 u; bf16 h[8]; } O;
        #pragma unroll
        for (int p = 0; p < 8; ++p) {
            float a1 = w1[0] * am[p] + w1[1] * am[p + 1] + w1[2] * am[p + 2]
                     + w1[3] * ac[p] + w1[4] * ac[p + 1] + w1[5] * ac[p + 2]
                     + w1[6] * ap[p] + w1[7] * ap[p + 1] + w1[8] * ap[p + 2];
            float a2 = w2[0] * bm[p] + w2[1] * bm[p + 1] + w2[2] * bm[p + 2]
                     + w2[3] * bc[p] + w2[4] * bc[p + 1] + w2[5] * bc[p + 2]
                     + w2[6] * bp[p] + w2[7] * bp[p + 1] + w2[8] * bp[p + 2];
            float gelu = 0.5f * a1 * (1.f + erff(a1 * 0.70710678118f));
            O.h[p] = __float2bfloat16(gelu * a2);
        }
        *(uint4*)(y + (ybase + j) * 128 + x0) = O.u;
    }
}

// ==================== host ====================
extern "C" void kernel_launch(void* const* d_in, const int* in_sizes, int n_in,
                              void* d_out, int out_size, void* d_ws, size_t ws_size,
                              hipStream_t stream) {
    const float* x    = (const float*)d_in[0];
    const float* ln1w = (const float*)d_in[1];
    const float* ln1b = (const float*)d_in[2];
    const float* wq   = (const float*)d_in[3];
    const float* wk   = (const float*)d_in[4];
    const float* wv   = (const float*)d_in[5];
    const float* dwq  = (const float*)d_in[6];
    const float* dwk  = (const float*)d_in[7];
    const float* dwv  = (const float*)d_in[8];
    const float* temp = (const float*)d_in[9];
    const float* wo   = (const float*)d_in[10];
    const float* ln2w = (const float*)d_in[11];
    const float* ln2b = (const float*)d_in[12];
    const float* w_in = (const float*)d_in[13];
    const float* dwf  = (const float*)d_in[14];
    const float* wout = (const float*)d_in[15];
    float* out = (float*)d_out;
    char* ws = (char*)d_ws;

    float* mu    = (float*)(ws + OFF_MU);
    float* rstd  = (float*)(ws + OFF_RSTD);
    float* mu2   = (float*)(ws + OFF_MU2);
    float* rstd2 = (float*)(ws + OFF_RSTD2);
    float* ssq   = (float*)(ws + OFF_SSQ);
    float* S     = (float*)(ws + OFF_S);
    float* dwp   = (float*)(ws + OFF_DWP);
    bf16*  Wqkvb = (bf16*)(ws + OFF_WQKVB);
    bf16*  winb  = (bf16*)(ws + OFF_WINB);
    bf16*  woutb = (bf16*)(ws + OFF_WOUTB);
    bf16*  Weffb = (bf16*)(ws + OFF_WEFFB);
    bf16*  x2b   = (bf16*)(ws + OFF_X2B);
    bf16*  qkv   = (bf16*)(ws + OFF_QKV);
    bf16*  qkvdw = (bf16*)(ws + OFF_QKVDW);
    bf16*  g     = (bf16*)(ws + OFF_G);
    bf16*  y     = (bf16*)(ws + OFF_Y);

    const size_t XB = (size_t)CDIM * NPIX;
    const size_t QB = (size_t)384 * NPIX;

    hipMemsetAsync(ws + OFF_SSQ, 0, 73728, stream);  // ssq + S
    pack_w<<<512, 256, 0, stream>>>(wq, wk, wv, dwq, dwk, dwv, w_in, wout,
                                    Wqkvb, dwp, winb, woutb);

    // ---- Phase A: attention, all 8 batches ----
    ln_stats<float><<<dim3(64, 8), 256, 0, stream>>>(x, XB, mu, rstd);
    gemm_mfma<float, bf16, float, true, false><<<dim3(6, 128, 8), 256, 0, stream>>>(
        Wqkvb, 0, x, XB, mu, rstd, ln1w, ln1b, nullptr, 0, qkv, QB, 128);
    dwconv_qkv<<<dim3(384, 8), 256, 0, stream>>>(qkv, qkvdw, dwp, ssq);
    attn_scores<<<dim3(8, 8, 8), 256, 0, stream>>>(qkvdw, S);
    softmax_weff<<<8, 256, 0, stream>>>(S, ssq, temp, wo, Weffb);
    gemm_mfma<bf16, bf16, float, false, true><<<dim3(2, 128, 8), 256, 0, stream>>>(
        Weffb, 16384, qkvdw + (size_t)256 * NPIX, QB, nullptr, nullptr, nullptr, nullptr,
        x, XB, x2b, XB, 128);
    ln_stats<bf16><<<dim3(64, 8), 256, 0, stream>>>(x2b, XB, mu2, rstd2);

    // ---- Phase B: FFN, two groups of 4 batches (g/y overlay dead qkv/qkvdw) ----
    for (int grp = 0; grp < 2; ++grp) {
        const bf16* x2g = x2b + (size_t)grp * 4 * XB;
        gemm_mfma<bf16, bf16, float, true, false><<<dim3(16, 128, 4), 256, 0, stream>>>(
            winb, 0, x2g, XB, mu2 + (size_t)grp * 4 * NPIX, rstd2 + (size_t)grp * 4 * NPIX,
            ln2w, ln2b, nullptr, 0, g, (size_t)1024 * NPIX, 128);
        geglu_dw<<<dim3(512, 4), 256, 0, stream>>>(g, y, dwf);
        gemm_mfma<bf16, float, bf16, false, true><<<dim3(2, 128, 4), 256, 0, stream>>>(
            woutb, 0, y, (size_t)512 * NPIX, nullptr, nullptr, nullptr, nullptr,
            x2g, XB, out + (size_t)grp * 4 * XB, XB, 512);
    }
    (void)in_sizes; (void)n_in; (void)out_size; (void)ws_size;
}

// Round 13
// 590.102 us; speedup vs baseline: 7.4970x; 1.1739x over previous
//
#include <hip/hip_runtime.h>
#include <hip/hip_bf16.h>
#include <type_traits>

using bf16 = __hip_bfloat16;
using f32x4  = __attribute__((ext_vector_type(4))) float;
using bf16x8 = __attribute__((ext_vector_type(8))) short;

constexpr int NPIX = 16384;   // pixels per batch (128*128)
constexpr int CDIM = 128;

// ---- workspace offsets (bytes); ws_size = 256 MiB ----
constexpr size_t OFF_MU    = 0;          // 8*16384 f32
constexpr size_t OFF_RSTD  = 524288;     // 8*16384 f32
constexpr size_t OFF_MU2   = 1048576;    // 8*16384 f32
constexpr size_t OFF_RSTD2 = 1572864;    // 8*16384 f32
constexpr size_t OFF_SSQ   = 2097152;    // 8*256 f32
constexpr size_t OFF_S     = 2105344;    // 8*2048 f32
constexpr size_t OFF_DWP   = 2170880;    // 384*9 f32
constexpr size_t OFF_WQKVB = 2184704;    // 384*128 bf16
constexpr size_t OFF_WINB  = 2283008;    // 1024*128 bf16
constexpr size_t OFF_WOUTB = 2545152;    // 128*512 bf16
constexpr size_t OFF_WEFFB = 2676224;    // 8*128*128 bf16
constexpr size_t OFF_X2B   = 2938368;    // 8*128*16384 bf16 (33.55 MB)
constexpr size_t OFF_QKV   = 36492800;   // 8*384*16384 bf16 (100.7 MB)
constexpr size_t OFF_QKVDW = 137156096;  // 8*384*16384 bf16 (100.7 MB) -> ends 237819392
// Phase B overlays (qkv/qkvdw dead): 4 batches per group
constexpr size_t OFF_G     = 36492800;   // 4*1024*16384 bf16 (134.2 MB)
constexpr size_t OFF_Y     = 170710528;  // 4*512*16384 bf16 (67.1 MB); xn2 (16.8 MB) overlays
                                         // this region during ln2norm/w_in (dead before geglu writes y)

__device__ inline float ldf(const float* p) { return *p; }
__device__ inline float ldf(const bf16* p) { return __bfloat162float(*p); }

// -------------------- pack weights to bf16 --------------------
__global__ void pack_w(const float* __restrict__ wq, const float* __restrict__ wk,
                       const float* __restrict__ wv, const float* __restrict__ dwq,
                       const float* __restrict__ dwk, const float* __restrict__ dwv,
                       const float* __restrict__ w_in, const float* __restrict__ wout,
                       bf16* __restrict__ Wqkvb, float* __restrict__ dwp,
                       bf16* __restrict__ winb, bf16* __restrict__ woutb) {
    int i = blockIdx.x * 256 + threadIdx.x;   // grid 512 -> 131072
    if (i < 384 * 128) {
        int r = i >> 7, c = i & 127;
        float v = (r < 128) ? wq[r * 128 + c] : (r < 256) ? wk[(r - 128) * 128 + c]
                                                          : wv[(r - 256) * 128 + c];
        Wqkvb[i] = __float2bfloat16(v);
    }
    if (i < 384 * 9) {
        int r = i / 9, j = i % 9;
        dwp[i] = (r < 128) ? dwq[r * 9 + j] : (r < 256) ? dwk[(r - 128) * 9 + j]
                                                        : dwv[(r - 256) * 9 + j];
    }
    if (i < 1024 * 128) winb[i] = __float2bfloat16(w_in[i]);
    if (i < 128 * 512)  woutb[i] = __float2bfloat16(wout[i]);
}

// -------------------- LayerNorm stats, batched over blockIdx.y --------------------
template <typename XT>
__global__ __launch_bounds__(256) void ln_stats(const XT* __restrict__ X, size_t xBs,
                                                float* __restrict__ mu,
                                                float* __restrict__ rstd) {
    const int b = blockIdx.y;
    const XT* Xb = X + (size_t)b * xBs;
    int n = blockIdx.x * 256 + threadIdx.x;
    float s = 0.f, s2 = 0.f;
    for (int c = 0; c < CDIM; ++c) {
        float v = ldf(&Xb[(size_t)c * NPIX + n]);
        s += v; s2 += v * v;
    }
    float m = s * (1.f / CDIM);
    float var = s2 * (1.f / CDIM) - m * m;
    mu[b * NPIX + n] = m;
    rstd[b * NPIX + n] = rsqrtf(var + 1e-5f);
}

// -------------------- LN2 normalize to bf16: xn[c][n] = (x2-mu)*rstd*lw[c]+lb[c] ------
// grid (1024 blocks, nb batches); thread: 8 consecutive px of one channel.
__global__ __launch_bounds__(256) void ln2norm(const bf16* __restrict__ x2, size_t xBs,
                                               const float* __restrict__ mu,
                                               const float* __restrict__ rstd,
                                               const float* __restrict__ lnw,
                                               const float* __restrict__ lnb,
                                               bf16* __restrict__ xn) {
    const int b = blockIdx.y;
    const int id = blockIdx.x * 256 + threadIdx.x;
    const int c = id >> 11, n8 = (id & 2047) * 8;
    const bf16* src = x2 + (size_t)b * xBs + (size_t)c * NPIX + n8;
    bf16* dst = xn + (size_t)b * xBs + (size_t)c * NPIX + n8;
    const float* mup = mu + (size_t)b * NPIX + n8;
    const float* rsp = rstd + (size_t)b * NPIX + n8;
    float lw = lnw[c], lb = lnb[c];
    union { uint4 u; bf16 h[8]; } V, O;
    V.u = *(const uint4*)src;
    float4 m0 = *(const float4*)mup, m1 = *(const float4*)(mup + 4);
    float4 r0 = *(const float4*)rsp, r1 = *(const float4*)(rsp + 4);
    float mm[8] = {m0.x, m0.y, m0.z, m0.w, m1.x, m1.y, m1.z, m1.w};
    float rr[8] = {r0.x, r0.y, r0.z, r0.w, r1.x, r1.y, r1.z, r1.w};
    #pragma unroll
    for (int j = 0; j < 8; ++j)
        O.h[j] = __float2bfloat16((__bfloat162float(V.h[j]) - mm[j]) * rr[j] * lw + lb);
    *(uint4*)dst = O.u;
}

// ---------------- MFMA GEMM, batched, XCD-swizzled ----------
// out[m,n] = sum_k W[m,k]*X[k,n] (+res, +LN-on-X). tile 64M x 128N, K-step 32.
// Fast path XT==bf16 && !LN: raw short staging (no float round-trip).
template <typename XT, typename OT, typename RT, bool LN, bool RES>
__global__ __launch_bounds__(256) void gemm_mfma(
    const bf16* __restrict__ Wb0, int wBs, const XT* __restrict__ X0, size_t xBs,
    const float* __restrict__ mu0, const float* __restrict__ rstd0,
    const float* __restrict__ lnw, const float* __restrict__ lnb,
    const RT* __restrict__ res0, size_t rBs, OT* __restrict__ out0, size_t oBs, int K) {
    __shared__ bf16 Wl[64][40];    // [m][k]
    __shared__ bf16 Xt[128][40];   // [n][k] transposed
    const int t = threadIdx.x;

    // bijective XCD swizzle (m204): contiguous work chunk per XCD for X-slice L2 reuse
    const int gx = gridDim.x, gy = gridDim.y;
    const int nwg = gx * gy * gridDim.z;
    const int flat = blockIdx.x + gx * (blockIdx.y + gy * blockIdx.z);
    const int q = nwg >> 3, r8 = nwg & 7;
    const int xcd = flat & 7, idx = flat >> 3;
    const int wid = (xcd < r8 ? xcd * (q + 1) : r8 * (q + 1) + (xcd - r8) * q) + idx;
    const int mb = wid % gx, rest = wid / gx;
    const int nb = rest % gy, b = rest / gy;

    const bf16* Wb = Wb0 + (size_t)b * wBs;
    const XT* X = X0 + (size_t)b * xBs;
    const RT* res = RES ? res0 + (size_t)b * rBs : nullptr;
    OT* out = out0 + (size_t)b * oBs;
    const float* mu = LN ? mu0 + (size_t)b * NPIX : nullptr;
    const float* rstd = LN ? rstd0 + (size_t)b * NPIX : nullptr;

    const int lane = t & 63, wave = t >> 6;
    const int wm = wave >> 1, wn = wave & 1;
    const int g = lane >> 4, lr = lane & 15;
    const int m0 = mb * 64, n0 = nb * 128;

    const int sw_row = t >> 2, sw_k8 = (t & 3) * 8;
    const int sx_n = t & 127, sx_kh = t >> 7;

    float x_mu = 0.f, x_rs = 0.f;
    if constexpr (LN) { x_mu = mu[n0 + sx_n]; x_rs = rstd[n0 + sx_n]; }

    f32x4 acc[2][4];
    #pragma unroll
    for (int i = 0; i < 2; ++i)
        #pragma unroll
        for (int j = 0; j < 4; ++j)
            acc[i][j] = (f32x4){0.f, 0.f, 0.f, 0.f};

    for (int kc = 0; kc < K; kc += 32) {
        uint4 wv = *(const uint4*)(Wb + (size_t)(m0 + sw_row) * K + kc + sw_k8);
        *(uint4*)&Wl[sw_row][sw_k8] = wv;
        {
            union { uint4 u[2]; bf16 h[16]; } T;
            const int kb = kc + sx_kh * 16;
            const XT* xp = X + (size_t)kb * NPIX + n0 + sx_n;
            if constexpr (std::is_same_v<XT, bf16> && !LN) {
                #pragma unroll
                for (int kk = 0; kk < 16; ++kk)
                    T.h[kk] = xp[(size_t)kk * NPIX];          // raw bf16 copy, no cvt
            } else {
                #pragma unroll
                for (int kk = 0; kk < 16; ++kk) {
                    float v = ldf(&xp[(size_t)kk * NPIX]);
                    if constexpr (LN) v = (v - x_mu) * x_rs * lnw[kb + kk] + lnb[kb + kk];
                    T.h[kk] = __float2bfloat16(v);
                }
            }
            *(uint4*)&Xt[sx_n][sx_kh * 16] = T.u[0];
            *(uint4*)&Xt[sx_n][sx_kh * 16 + 8] = T.u[1];
        }
        __syncthreads();
        bf16x8 af[2], bfr[4];
        #pragma unroll
        for (int i = 0; i < 2; ++i)
            af[i] = *(const bf16x8*)&Wl[wm * 32 + i * 16 + lr][g * 8];
        #pragma unroll
        for (int j = 0; j < 4; ++j)
            bfr[j] = *(const bf16x8*)&Xt[wn * 64 + j * 16 + lr][g * 8];
        #pragma unroll
        for (int i = 0; i < 2; ++i)
            #pragma unroll
            for (int j = 0; j < 4; ++j)
                acc[i][j] = __builtin_amdgcn_mfma_f32_16x16x32_bf16(af[i], bfr[j], acc[i][j], 0, 0, 0);
        __syncthreads();
    }
    #pragma unroll
    for (int i = 0; i < 2; ++i) {
        #pragma unroll
        for (int j = 0; j < 4; ++j) {
            #pragma unroll
            for (int r = 0; r < 4; ++r) {
                int row = m0 + wm * 32 + i * 16 + g * 4 + r;
                int col = n0 + wn * 64 + j * 16 + lr;
                float v = acc[i][j][r];
                if constexpr (RES) v += ldf(&res[(size_t)row * NPIX + col]);
                if constexpr (std::is_same_v<OT, float>)
                    out[(size_t)row * NPIX + col] = v;
                else
                    out[(size_t)row * NPIX + col] = __float2bfloat16(v);
            }
        }
    }
}

// ---------- depthwise 3x3 (qkv), 8-row strip/thread, rolling registers ----------
__global__ __launch_bounds__(256) void dwconv_qkv(const bf16* __restrict__ in0,
                                                  bf16* __restrict__ out0,
                                                  const float* __restrict__ w9,
                                                  float* __restrict__ ssq0) {
    const int b = blockIdx.y, c = blockIdx.x;
    const bf16* in = in0 + ((size_t)b * 384 + c) * NPIX;
    bf16* out = out0 + ((size_t)b * 384 + c) * NPIX;
    float* ssq = ssq0 + b * 256;
    const int t = threadIdx.x;
    const int lane = t & 63;
    const int tx = t & 15, ty = t >> 4;
    const int x0 = tx * 8, ybase = ty * 8;
    float w[9];
    #pragma unroll
    for (int j = 0; j < 9; ++j) w[j] = w9[c * 9 + j];

    float r[3][10];
    auto loadrow = [&](int yy, float* d) {
        union { uint4 u; bf16 h[8]; } V;
        bool ok = (yy >= 0 && yy <= 127);
        V.u = ok ? *(const uint4*)(in + yy * 128 + x0) : make_uint4(0u, 0u, 0u, 0u);
        #pragma unroll
        for (int j = 0; j < 8; ++j) d[j + 1] = __bfloat162float(V.h[j]);
        float Lv = __shfl(d[8], lane - 1, 64);
        float Rv = __shfl(d[1], lane + 1, 64);
        d[0] = (tx == 0) ? 0.f : Lv;
        d[9] = (tx == 15) ? 0.f : Rv;
    };

    loadrow(ybase - 1, r[0]);
    loadrow(ybase, r[1]);
    float s2 = 0.f;
    #pragma unroll
    for (int j = 0; j < 8; ++j) {
        loadrow(ybase + j + 1, r[(j + 2) % 3]);
        const float* rm = r[j % 3];
        const float* rc = r[(j + 1) % 3];
        const float* rp = r[(j + 2) % 3];
        union { uint4 u; bf16 h[8]; } O;
        #pragma unroll
        for (int p = 0; p < 8; ++p) {
            float a = w[0] * rm[p] + w[1] * rm[p + 1] + w[2] * rm[p + 2]
                    + w[3] * rc[p] + w[4] * rc[p + 1] + w[5] * rc[p + 2]
                    + w[6] * rp[p] + w[7] * rp[p + 1] + w[8] * rp[p + 2];
            s2 = fmaf(a, a, s2);
            O.h[p] = __float2bfloat16(a);
        }
        *(uint4*)(out + (ybase + j) * 128 + x0) = O.u;
    }
    if (c < 256) {
        #pragma unroll
        for (int off = 32; off; off >>= 1) s2 += __shfl_down(s2, off);
        if (lane == 0) atomicAdd(&ssq[c], s2);
    }
}

// -------------------- attention scores via MFMA --------------------
__global__ __launch_bounds__(256) void attn_scores(const bf16* __restrict__ qkvdw0,
                                                   float* __restrict__ S0) {
    const int b = blockIdx.z;
    const bf16* base = qkvdw0 + (size_t)b * 384 * NPIX;
    float* S = S0 + b * 2048;
    const int h = blockIdx.x;
    const int n00 = blockIdx.y * 2048;
    __shared__ bf16 ql[16][264], kl[16][264];
    __shared__ float sacc[4][256];
    const int t = threadIdx.x;
    const int lane = t & 63, wave = t >> 6;
    const int lr = lane & 15, g = lane >> 4;
    const bf16* qbase = base + (size_t)(h * 16) * NPIX;
    const bf16* kbase = base + (size_t)(128 + h * 16) * NPIX;

    f32x4 acc = (f32x4){0.f, 0.f, 0.f, 0.f};
    for (int it = 0; it < 8; ++it) {
        const int n0 = n00 + it * 256;
        __syncthreads();
        #pragma unroll
        for (int s = 0; s < 2; ++s) {
            int idx = t + s * 256;
            int row = idx >> 5, cc = (idx & 31) * 8;
            *(uint4*)&ql[row][cc] = *(const uint4*)(qbase + (size_t)row * NPIX + n0 + cc);
            *(uint4*)&kl[row][cc] = *(const uint4*)(kbase + (size_t)row * NPIX + n0 + cc);
        }
        __syncthreads();
        #pragma unroll
        for (int m = 0; m < 2; ++m) {
            const int kc = wave * 64 + m * 32 + g * 8;
            bf16x8 aq = *(const bf16x8*)&ql[lr][kc];
            bf16x8 bk = *(const bf16x8*)&kl[lr][kc];
            acc = __builtin_amdgcn_mfma_f32_16x16x32_bf16(aq, bk, acc, 0, 0, 0);
        }
    }
    #pragma unroll
    for (int r = 0; r < 4; ++r) {
        int d = g * 4 + r, e = lr;
        sacc[wave][d * 16 + e] = acc[r];
    }
    __syncthreads();
    float s = sacc[0][t] + sacc[1][t] + sacc[2][t] + sacc[3][t];
    atomicAdd(&S[h * 256 + t], s);
}

// -------------------- softmax + W_eff, one block per batch --------------------
__global__ __launch_bounds__(256) void softmax_weff(const float* __restrict__ S0,
                                                    const float* __restrict__ ssq0,
                                                    const float* __restrict__ temp,
                                                    const float* __restrict__ wo,
                                                    bf16* __restrict__ Weffb0) {
    const int b = blockIdx.x;
    const float* S = S0 + b * 2048;
    const float* ssq = ssq0 + b * 256;
    bf16* Weffb = Weffb0 + b * 16384;
    __shared__ float at[2048];
    __shared__ float rn[256];
    int t = threadIdx.x;
    rn[t] = 1.f / fmaxf(sqrtf(ssq[t]), 1e-12f);
    __syncthreads();
    for (int i = t; i < 2048; i += 256) {
        int hd = i >> 4, e = i & 15, h = hd >> 4;
        at[i] = S[i] * rn[hd] * rn[128 + h * 16 + e] * temp[h];
    }
    __syncthreads();
    if (t < 128) {
        float mx = -1e30f;
        for (int e = 0; e < 16; ++e) mx = fmaxf(mx, at[t * 16 + e]);
        float s = 0.f;
        for (int e = 0; e < 16; ++e) { float v = expf(at[t * 16 + e] - mx); at[t * 16 + e] = v; s += v; }
        float inv = 1.f / s;
        for (int e = 0; e < 16; ++e) at[t * 16 + e] *= inv;
    }
    __syncthreads();
    int o = t >> 1, half = t & 1;
    for (int j = 0; j < 64; ++j) {
        int col = half * 64 + j;
        int h16 = col & ~15, e = col & 15;
        float s = 0.f;
        #pragma unroll
        for (int dd = 0; dd < 16; ++dd)
            s = fmaf(wo[o * 128 + h16 + dd], at[(h16 + dd) * 16 + e], s);
        Weffb[o * 128 + col] = __float2bfloat16(s);
    }
}

// ---------- FFN depthwise 3x3 + GEGLU, 8-row strip/thread ----------
__global__ __launch_bounds__(256) void geglu_dw(const bf16* __restrict__ g0,
                                                bf16* __restrict__ y0,
                                                const float* __restrict__ dww) {
    const int b = blockIdx.y, c = blockIdx.x;
    const bf16* g1 = g0 + ((size_t)b * 1024 + c) * NPIX;
    const bf16* g2 = g0 + ((size_t)b * 1024 + c + 512) * NPIX;
    bf16* y = y0 + ((size_t)b * 512 + c) * NPIX;
    const int t = threadIdx.x;
    const int lane = t & 63;
    const int tx = t & 15, ty = t >> 4;
    const int x0 = tx * 8, ybase = ty * 8;
    float w1[9], w2[9];
    #pragma unroll
    for (int j = 0; j < 9; ++j) { w1[j] = dww[c * 9 + j]; w2[j] = dww[(c + 512) * 9 + j]; }

    float ra[3][10], rb[3][10];
    auto loadrow = [&](const bf16* src, int yy, float* d) {
        union { uint4 u; bf16 h[8]; } V;
        bool ok = (yy >= 0 && yy <= 127);
        V.u = ok ? *(const uint4*)(src + yy * 128 + x0) : make_uint4(0u, 0u, 0u, 0u);
        #pragma unroll
        for (int j = 0; j < 8; ++j) d[j + 1] = __bfloat162float(V.h[j]);
        float Lv = __shfl(d[8], lane - 1, 64);
        float Rv = __shfl(d[1], lane + 1, 64);
        d[0] = (tx == 0) ? 0.f : Lv;
        d[9] = (tx == 15) ? 0.f : Rv;
    };

    loadrow(g1, ybase - 1, ra[0]); loadrow(g1, ybase, ra[1]);
    loadrow(g2, ybase - 1, rb[0]); loadrow(g2, ybase, rb[1]);
    #pragma unroll
    for (int j = 0; j < 8; ++j) {
        loadrow(g1, ybase + j + 1, ra[(j + 2) % 3]);
        loadrow(g2, ybase + j + 1, rb[(j + 2) % 3]);
        const float* am = ra[j % 3]; const float* ac = ra[(j + 1) % 3]; const float* ap = ra[(j + 2) % 3];
        const float* bm = rb[j % 3]; const float* bc = rb[(j + 1) % 3]; const float* bp = rb[(j + 2) % 3];
        union { uint4 u; bf16 h[8]; } O;
        #pragma unroll
        for (int p = 0; p < 8; ++p) {
            float a1 = w1[0] * am[p] + w1[1] * am[p + 1] + w1[2] * am[p + 2]
                     + w1[3] * ac[p] + w1[4] * ac[p + 1] + w1[5] * ac[p + 2]
                     + w1[6] * ap[p] + w1[7] * ap[p + 1] + w1[8] * ap[p + 2];
            float a2 = w2[0] * bm[p] + w2[1] * bm[p + 1] + w2[2] * bm[p + 2]
                     + w2[3] * bc[p] + w2[4] * bc[p + 1] + w2[5] * bc[p + 2]
                     + w2[6] * bp[p] + w2[7] * bp[p + 1] + w2[8] * bp[p + 2];
            float gelu = 0.5f * a1 * (1.f + erff(a1 * 0.70710678118f));
            O.h[p] = __float2bfloat16(gelu * a2);
        }
        *(uint4*)(y + (ybase + j) * 128 + x0) = O.u;
    }
}

// ==================== host ====================
extern "C" void kernel_launch(void* const* d_in, const int* in_sizes, int n_in,
                              void* d_out, int out_size, void* d_ws, size_t ws_size,
                              hipStream_t stream) {
    const float* x    = (const float*)d_in[0];
    const float* ln1w = (const float*)d_in[1];
    const float* ln1b = (const float*)d_in[2];
    const float* wq   = (const float*)d_in[3];
    const float* wk   = (const float*)d_in[4];
    const float* wv   = (const float*)d_in[5];
    const float* dwq  = (const float*)d_in[6];
    const float* dwk  = (const float*)d_in[7];
    const float* dwv  = (const float*)d_in[8];
    const float* temp = (const float*)d_in[9];
    const float* wo   = (const float*)d_in[10];
    const float* ln2w = (const float*)d_in[11];
    const float* ln2b = (const float*)d_in[12];
    const float* w_in = (const float*)d_in[13];
    const float* dwf  = (const float*)d_in[14];
    const float* wout = (const float*)d_in[15];
    float* out = (float*)d_out;
    char* ws = (char*)d_ws;

    float* mu    = (float*)(ws + OFF_MU);
    float* rstd  = (float*)(ws + OFF_RSTD);
    float* mu2   = (float*)(ws + OFF_MU2);
    float* rstd2 = (float*)(ws + OFF_RSTD2);
    float* ssq   = (float*)(ws + OFF_SSQ);
    float* S     = (float*)(ws + OFF_S);
    float* dwp   = (float*)(ws + OFF_DWP);
    bf16*  Wqkvb = (bf16*)(ws + OFF_WQKVB);
    bf16*  winb  = (bf16*)(ws + OFF_WINB);
    bf16*  woutb = (bf16*)(ws + OFF_WOUTB);
    bf16*  Weffb = (bf16*)(ws + OFF_WEFFB);
    bf16*  x2b   = (bf16*)(ws + OFF_X2B);
    bf16*  qkv   = (bf16*)(ws + OFF_QKV);
    bf16*  qkvdw = (bf16*)(ws + OFF_QKVDW);
    bf16*  g     = (bf16*)(ws + OFF_G);
    bf16*  y     = (bf16*)(ws + OFF_Y);
    bf16*  xn2   = (bf16*)(ws + OFF_Y);   // overlays y; dead before geglu writes y

    const size_t XB = (size_t)CDIM * NPIX;
    const size_t QB = (size_t)384 * NPIX;

    hipMemsetAsync(ws + OFF_SSQ, 0, 73728, stream);  // ssq + S
    pack_w<<<512, 256, 0, stream>>>(wq, wk, wv, dwq, dwk, dwv, w_in, wout,
                                    Wqkvb, dwp, winb, woutb);

    // ---- Phase A: attention, all 8 batches ----
    ln_stats<float><<<dim3(64, 8), 256, 0, stream>>>(x, XB, mu, rstd);
    gemm_mfma<float, bf16, float, true, false><<<dim3(6, 128, 8), 256, 0, stream>>>(
        Wqkvb, 0, x, XB, mu, rstd, ln1w, ln1b, nullptr, 0, qkv, QB, 128);
    dwconv_qkv<<<dim3(384, 8), 256, 0, stream>>>(qkv, qkvdw, dwp, ssq);
    attn_scores<<<dim3(8, 8, 8), 256, 0, stream>>>(qkvdw, S);
    softmax_weff<<<8, 256, 0, stream>>>(S, ssq, temp, wo, Weffb);
    gemm_mfma<bf16, bf16, float, false, true><<<dim3(2, 128, 8), 256, 0, stream>>>(
        Weffb, 16384, qkvdw + (size_t)256 * NPIX, QB, nullptr, nullptr, nullptr, nullptr,
        x, XB, x2b, XB, 128);
    ln_stats<bf16><<<dim3(64, 8), 256, 0, stream>>>(x2b, XB, mu2, rstd2);

    // ---- Phase B: FFN, two groups of 4 batches (g/y overlay dead qkv/qkvdw) ----
    for (int grp = 0; grp < 2; ++grp) {
        const bf16* x2g = x2b + (size_t)grp * 4 * XB;
        const float* mu2g = mu2 + (size_t)grp * 4 * NPIX;
        const float* rs2g = rstd2 + (size_t)grp * 4 * NPIX;
        // pre-normalize LN2 -> bf16 (xn2 overlays y region)
        ln2norm<<<dim3(1024, 4), 256, 0, stream>>>(x2g, XB, mu2g, rs2g, ln2w, ln2b, xn2);
        // g = w_in @ xn2  (fast raw-bf16 staging path)
        gemm_mfma<bf16, bf16, float, false, false><<<dim3(16, 128, 4), 256, 0, stream>>>(
            winb, 0, xn2, XB, nullptr, nullptr, nullptr, nullptr, nullptr, 0,
            g, (size_t)1024 * NPIX, 128);
        geglu_dw<<<dim3(512, 4), 256, 0, stream>>>(g, y, dwf);
        gemm_mfma<bf16, float, bf16, false, true><<<dim3(2, 128, 4), 256, 0, stream>>>(
            woutb, 0, y, (size_t)512 * NPIX, nullptr, nullptr, nullptr, nullptr,
            x2g, XB, out + (size_t)grp * 4 * XB, XB, 512);
    }
    (void)in_sizes; (void)n_in; (void)out_size; (void)ws_size;
}